// Round 9
// baseline (1122.918 us; speedup 1.0000x reference)
//
#include <hip/hip_runtime.h>

// ---------------- problem constants ----------------
#define T_TOK 4096          // BB*L tokens
#define HID   2048
#define DI    4096
#define NH    64
#define PDIM  64
#define NSTATE 128
#define IM    8192
#define LSEQ  2048
#define CONVD 4352          // DI + 2*G*N
#define DPROJ 8512          // 2*DI + 2*G*N + NH
#define DPADR 8704          // padded to 34*256
#define QC    64            // SSD chunk length
#define NCH   32            // chunks per sequence

typedef __bf16 bf16x8 __attribute__((ext_vector_type(8)));
typedef float  f32x4  __attribute__((ext_vector_type(4)));

__device__ __forceinline__ unsigned short f2bf(float f) {
  unsigned u = __float_as_uint(f);
  u = (u + 0x7fffu + ((u >> 16) & 1u)) >> 16;
  return (unsigned short)u;
}
__device__ __forceinline__ float bf2f(unsigned short h) {
  return __uint_as_float(((unsigned)h) << 16);
}
__device__ __forceinline__ float siluf(float x) {
  return x / (1.f + __expf(-x));
}

#define GLL(gaddr, laddr) __builtin_amdgcn_global_load_lds( \
    (const __attribute__((address_space(1))) void*)(gaddr), \
    (__attribute__((address_space(3))) void*)(laddr), 16, 0, 0)

// ---------------- merged weight conversion (all 4 weights, 8 elems/thread) ----------------
__device__ __forceinline__ void cvt8(const float* __restrict__ s, unsigned short* __restrict__ d) {
  float4 v0 = *(const float4*)s;
  float4 v1 = *(const float4*)(s + 4);
  unsigned short o[8];
  o[0] = f2bf(v0.x); o[1] = f2bf(v0.y); o[2] = f2bf(v0.z); o[3] = f2bf(v0.w);
  o[4] = f2bf(v1.x); o[5] = f2bf(v1.y); o[6] = f2bf(v1.z); o[7] = f2bf(v1.w);
  *(uint4*)d = *(const uint4*)o;
}

// region thresholds in 8-elem units
#define CV_IN_END  2228224ULL   // DPADR*HID/8
#define CV_OUT_END 3276800ULL   // + 2048*4096/8
#define CV_GU_END  7471104ULL   // + 2*IM*2048/8
#define CV_DN_END  9568256ULL   // + 2048*8192/8

__global__ __launch_bounds__(256)
void k_cvt_all(const float* __restrict__ w_in, const float* __restrict__ w_out,
               const float* __restrict__ w_gu, const float* __restrict__ w_dn,
               unsigned short* __restrict__ d_in, unsigned short* __restrict__ d_out,
               unsigned short* __restrict__ d_gu, unsigned short* __restrict__ d_dn) {
  size_t gid = (size_t)blockIdx.x * 256 + threadIdx.x;
  if (gid < CV_IN_END) {
    size_t idx8 = gid * 8;
    int r = (int)(idx8 >> 11), k = (int)(idx8 & 2047);
    if (r < DPROJ) {
      cvt8(&w_in[(size_t)r * HID + k], d_in + idx8);
    } else {
      uint4 z = {0, 0, 0, 0};
      *(uint4*)(d_in + idx8) = z;
    }
  } else if (gid < CV_OUT_END) {
    size_t idx8 = (gid - CV_IN_END) * 8;
    cvt8(w_out + idx8, d_out + idx8);
  } else if (gid < CV_GU_END) {
    size_t idx8 = (gid - CV_OUT_END) * 8;
    int r = (int)(idx8 >> 11), k = (int)(idx8 & 2047);
    int g = r >> 6, j = r & 63;
    int srcr = (j < 32) ? (g * 32 + j) : (IM + g * 32 + (j - 32));
    cvt8(&w_gu[(size_t)srcr * HID + k], d_gu + idx8);
  } else if (gid < CV_DN_END) {
    size_t idx8 = (gid - CV_GU_END) * 8;
    cvt8(w_dn + idx8, d_dn + idx8);
  }
}

// ---------------- 128x256xBK32 GEMM, 2 blocks/CU ----------------
// C[M,N] = A[M,K] * W[N,K]^T, M fixed 4096 (NTM=32). 512 thr = 8 waves (2M x 4N),
// per-wave 64x64 (acc 64 VGPR). LDS 48KB/block (2 x 24KB dbuf) -> with
// __launch_bounds__(512,4) TWO independent blocks/CU: their barriers are
// unsynchronized, so one block's MFMA burst overlaps the other's LDS burst
// (fixes the measured read/MFMA serialization of the 1-block 256^2 kernel).
// BK=32: every ds_read frag and every global_load_lds write is a contiguous
// 1KB wave access -> conflict-free with LINEAR layout, no swizzle.
// R5-verified loop shape: 1 barrier + 1 vmcnt(0) per K-tile (waits loads
// issued a full tile earlier), reads interleaved with MFMA clusters.
// EPI: 0 = bf16 store, 1 = f32 + resid, 2 = gate-pair silu bf16, 3 = f32 store
template <int EPI>
__global__ __launch_bounds__(512, 4)
void gemmk(const unsigned short* __restrict__ A, const unsigned short* __restrict__ W,
           int K, int ldo, void* __restrict__ outp,
           const float* __restrict__ resid) {
  constexpr int ABYT = 8192;            // 128 rows x 32 elems x 2B
  constexpr int BBYT = 16384;           // 256 rows x 32 elems x 2B
  constexpr int BUFB = ABYT + BBYT;     // 24576
  constexpr int NTM  = 32;
  __shared__ __align__(16) char smem[2 * BUFB];
  const int t = threadIdx.x;
  const int w = t >> 6, l = t & 63;
  const int lr = l & 15, hi = l >> 4;
  const int wr = w >> 2, wc = w & 3;

  // T1: bijective XCD swizzle over tn-major enumeration (grid % 8 == 0)
  const int q8 = (int)gridDim.x >> 3;
  const int bid = blockIdx.x;
  const int id2 = (bid & 7) * q8 + (bid >> 3);
  const int tn = id2 / NTM, tm = id2 % NTM;
  const int m0b = tm << 7, n0b = tn << 8;

  // staging: 4 threads/row (64B), rows 0..127 per unit; linear LDS dst
  const unsigned short* Ag = A + (size_t)(m0b + (t >> 2)) * K + (t & 3) * 8;
  const unsigned short* Wg = W + (size_t)(n0b + (t >> 2)) * K + (t & 3) * 8;

  // ds_read bases: frag = 16 rows x 64B = contiguous 1KB
  const int aoffc = (wr * 64 + lr) * 64 + hi * 16;
  const int boffc = ABYT + (wc * 64 + lr) * 64 + hi * 16;

#define ISSUE_A(jt, bb) GLL(Ag + (size_t)(jt) * 32, smem + (bb) * BUFB + t * 16)
#define ISSUE_B(jt, bb) do {                                                    \
    GLL(Wg + (size_t)(jt) * 32, smem + (bb) * BUFB + ABYT + t * 16);            \
    GLL(Wg + (size_t)128 * K + (size_t)(jt) * 32,                               \
        smem + (bb) * BUFB + ABYT + 8192 + t * 16); } while (0)

#define RDF(off, base) (*(const bf16x8*)((base) + (off)))
#define MF2(P, x, y) do {                                                                     \
    __builtin_amdgcn_s_setprio(1);                                                            \
    acc[2*(P)  ][0] = __builtin_amdgcn_mfma_f32_16x16x32_bf16((x), b0, acc[2*(P)  ][0],0,0,0);\
    acc[2*(P)+1][0] = __builtin_amdgcn_mfma_f32_16x16x32_bf16((y), b0, acc[2*(P)+1][0],0,0,0);\
    acc[2*(P)  ][1] = __builtin_amdgcn_mfma_f32_16x16x32_bf16((x), b1, acc[2*(P)  ][1],0,0,0);\
    acc[2*(P)+1][1] = __builtin_amdgcn_mfma_f32_16x16x32_bf16((y), b1, acc[2*(P)+1][1],0,0,0);\
    acc[2*(P)  ][2] = __builtin_amdgcn_mfma_f32_16x16x32_bf16((x), b2, acc[2*(P)  ][2],0,0,0);\
    acc[2*(P)+1][2] = __builtin_amdgcn_mfma_f32_16x16x32_bf16((y), b2, acc[2*(P)+1][2],0,0,0);\
    acc[2*(P)  ][3] = __builtin_amdgcn_mfma_f32_16x16x32_bf16((x), b3, acc[2*(P)  ][3],0,0,0);\
    acc[2*(P)+1][3] = __builtin_amdgcn_mfma_f32_16x16x32_bf16((y), b3, acc[2*(P)+1][3],0,0,0);\
    __builtin_amdgcn_s_setprio(0); } while (0)

  f32x4 acc[4][4];
#pragma unroll
  for (int m = 0; m < 4; m++)
#pragma unroll
    for (int n = 0; n < 4; n++) acc[m][n] = (f32x4){0.f, 0.f, 0.f, 0.f};

  const int nkt = K >> 5;
  // prologue: stage tile 0 into buf 0
  ISSUE_A(0, 0); ISSUE_B(0, 0);

  for (int j = 0; j < nkt; ++j) {
    const char* Ab = smem + (size_t)(j & 1) * BUFB;
    const int nb = (j & 1) ^ 1;
    asm volatile("s_waitcnt vmcnt(0)" ::: "memory");   // waits loads issued a full tile ago
    __builtin_amdgcn_s_barrier();
    __builtin_amdgcn_sched_barrier(0);
    if (j + 1 < nkt) { ISSUE_A(j + 1, nb); ISSUE_B(j + 1, nb); }
    bf16x8 b0 = RDF(boffc, Ab), b1 = RDF(boffc + 1024, Ab),
           b2 = RDF(boffc + 2048, Ab), b3 = RDF(boffc + 3072, Ab);
    bf16x8 a0 = RDF(aoffc, Ab), a1 = RDF(aoffc + 1024, Ab);
    MF2(0, a0, a1);
    bf16x8 a2 = RDF(aoffc + 2048, Ab), a3 = RDF(aoffc + 3072, Ab);
    MF2(1, a2, a3);
  }

  if constexpr (EPI == 0) {
    unsigned short* op = (unsigned short*)outp;
#pragma unroll
    for (int m = 0; m < 4; m++)
#pragma unroll
      for (int n = 0; n < 4; n++)
#pragma unroll
        for (int r = 0; r < 4; r++) {
          int row = m0b + wr * 64 + m * 16 + hi * 4 + r;
          int col = n0b + wc * 64 + n * 16 + lr;
          op[(size_t)row * ldo + col] = f2bf(acc[m][n][r]);
        }
  } else if constexpr (EPI == 2) {
    unsigned short* op = (unsigned short*)outp;
    const int gbase = (n0b + wc * 64) >> 1;
#pragma unroll
    for (int m = 0; m < 4; m++)
#pragma unroll
      for (int n = 0; n < 2; n++)
#pragma unroll
        for (int r = 0; r < 4; r++) {
          int row = m0b + wr * 64 + m * 16 + hi * 4 + r;
          int col = gbase + n * 16 + lr;
          float g = acc[m][n][r], u = acc[m][n + 2][r];
          op[(size_t)row * ldo + col] = f2bf(siluf(g) * u);
        }
  } else {
    float* op = (float*)outp;
#pragma unroll
    for (int m = 0; m < 4; m++)
#pragma unroll
      for (int n = 0; n < 4; n++)
#pragma unroll
        for (int r = 0; r < 4; r++) {
          int row = m0b + wr * 64 + m * 16 + hi * 4 + r;
          int col = n0b + wc * 64 + n * 16 + lr;
          float v = acc[m][n][r];
          if constexpr (EPI == 1) v += resid[(size_t)row * ldo + col];
          op[(size_t)row * ldo + col] = v;
        }
  }
#undef ISSUE_A
#undef ISSUE_B
#undef RDF
#undef MF2
}

// ---------------- norms ----------------
__device__ __forceinline__ float block_reduce_sum256(float v, float* sred) {
#pragma unroll
  for (int m = 32; m; m >>= 1) v += __shfl_xor(v, m);
  int t = threadIdx.x;
  if ((t & 63) == 0) sred[t >> 6] = v;
  __syncthreads();
  return sred[0] + sred[1] + sred[2] + sred[3];
}

__global__ __launch_bounds__(256)
void k_addnorm(const float* __restrict__ hin, const float* __restrict__ rin,
               const float* __restrict__ wln, float* __restrict__ rout,
               unsigned short* __restrict__ hbf) {
  __shared__ float sred[4];
  const int tok = blockIdx.x, t = threadIdx.x;
  const size_t base = (size_t)tok * HID + t * 8;
  float4 a0 = *(const float4*)&hin[base];
  float4 a1 = *(const float4*)&hin[base + 4];
  float4 b0 = *(const float4*)&rin[base];
  float4 b1 = *(const float4*)&rin[base + 4];
  float v[8] = {a0.x + b0.x, a0.y + b0.y, a0.z + b0.z, a0.w + b0.w,
                a1.x + b1.x, a1.y + b1.y, a1.z + b1.z, a1.w + b1.w};
  float ss = 0.f;
#pragma unroll
  for (int j = 0; j < 8; j++) ss += v[j] * v[j];
  float tot = block_reduce_sum256(ss, sred);
  float rms = rsqrtf(tot * (1.f / HID) + 1e-5f);
  *(float4*)&rout[base] = (float4){v[0], v[1], v[2], v[3]};
  *(float4*)&rout[base + 4] = (float4){v[4], v[5], v[6], v[7]};
  float4 w0 = *(const float4*)&wln[t * 8];
  float4 w1 = *(const float4*)&wln[t * 8 + 4];
  float wa[8] = {w0.x, w0.y, w0.z, w0.w, w1.x, w1.y, w1.z, w1.w};
  unsigned short o[8];
#pragma unroll
  for (int j = 0; j < 8; j++) o[j] = f2bf(v[j] * rms * wa[j]);
  *(ushort4*)&hbf[base] = *(ushort4*)&o[0];
  *(ushort4*)&hbf[base + 4] = *(ushort4*)&o[4];
}

__global__ __launch_bounds__(256)
void k_rmsnorm_bf(const float* __restrict__ src, const float* __restrict__ wln,
                  unsigned short* __restrict__ dst) {
  __shared__ float sred[4];
  const int tok = blockIdx.x, t = threadIdx.x;
  const size_t base = (size_t)tok * HID + t * 8;
  float4 a0 = *(const float4*)&src[base];
  float4 a1 = *(const float4*)&src[base + 4];
  float v[8] = {a0.x, a0.y, a0.z, a0.w, a1.x, a1.y, a1.z, a1.w};
  float ss = 0.f;
#pragma unroll
  for (int j = 0; j < 8; j++) ss += v[j] * v[j];
  float tot = block_reduce_sum256(ss, sred);
  float rms = rsqrtf(tot * (1.f / HID) + 1e-5f);
  float4 w0 = *(const float4*)&wln[t * 8];
  float4 w1 = *(const float4*)&wln[t * 8 + 4];
  float wa[8] = {w0.x, w0.y, w0.z, w0.w, w1.x, w1.y, w1.z, w1.w};
  unsigned short o[8];
#pragma unroll
  for (int j = 0; j < 8; j++) o[j] = f2bf(v[j] * rms * wa[j]);
  *(ushort4*)&dst[base] = *(ushort4*)&o[0];
  *(ushort4*)&dst[base + 4] = *(ushort4*)&o[4];
}

__global__ __launch_bounds__(256)
void k_gatenorm(const unsigned short* __restrict__ ybuf, const unsigned short* __restrict__ projbf,
                const float* __restrict__ wmix, unsigned short* __restrict__ ynorm) {
  __shared__ float sred[4];
  const int tok = blockIdx.x, t = threadIdx.x;
  const size_t yb = (size_t)tok * DI;
  const size_t pb = (size_t)tok * DPADR;
  float g[16];
  float ss = 0.f;
#pragma unroll
  for (int j = 0; j < 16; j++) {
    int idx = j * 256 + t;
    float yv = bf2f(ybuf[yb + idx]);
    float z = bf2f(projbf[pb + idx]);
    float gg = yv * siluf(z);
    g[j] = gg;
    ss += gg * gg;
  }
  float tot = block_reduce_sum256(ss, sred);
  float rms = rsqrtf(tot * (1.f / DI) + 1e-5f);
#pragma unroll
  for (int j = 0; j < 16; j++) {
    int idx = j * 256 + t;
    ynorm[yb + idx] = f2bf(g[j] * rms * wmix[idx]);
  }
}

// ---------------- conv (depthwise causal K=4) + silu + fused dt softplus ----------------
__global__ __launch_bounds__(256)
void k_conv(const unsigned short* __restrict__ projbf, const float* __restrict__ cw,
            const float* __restrict__ cb, const float* __restrict__ dt_bias,
            unsigned short* __restrict__ xbf, unsigned short* __restrict__ bcbf,
            float* __restrict__ dtg) {
  const int c = blockIdx.x * 256 + threadIdx.x;   // 0..4607
  const int tk = blockIdx.y;                      // token
  if (c < CONVD) {
    const int lpos = tk & (LSEQ - 1);
    float4 wv = *(const float4*)&cw[c * 4];
    float wk[4] = {wv.x, wv.y, wv.z, wv.w};
    float acc = cb[c];
#pragma unroll
    for (int k = 0; k < 4; k++) {
      int lp = lpos - 3 + k;
      if (lp >= 0) acc += bf2f(projbf[(size_t)(tk - 3 + k) * DPADR + DI + c]) * wk[k];
    }
    unsigned short r = f2bf(siluf(acc));
    if (c < DI) xbf[(size_t)tk * DI + c] = r;
    else        bcbf[(size_t)tk * 256 + (c - DI)] = r;
  } else if (c < CONVD + NH) {
    const int hh = c - CONVD;
    float x = bf2f(projbf[(size_t)tk * DPADR + DI + c]) + dt_bias[hh];
    float dt = (x > 20.f) ? x : log1pf(__expf(x));
    dtg[(size_t)tk * NH + hh] = dt;
  }
}

// ---------------- SSD kernel 1: per (b,h,chunk) intra + chunk-state ----------------
__global__ __launch_bounds__(256)
void k_ssd1(const unsigned short* __restrict__ xbf, const unsigned short* __restrict__ bcbf,
            const float* __restrict__ dtg, const float* __restrict__ A_log,
            const float* __restrict__ Dv, unsigned short* __restrict__ ybuf,
            unsigned short* __restrict__ Sc, float* __restrict__ dtsum) {
  __shared__ __align__(16) char smem[60928];
  unsigned short* sBs  = (unsigned short*)(smem);          // [64][128]
  unsigned short* sCs  = (unsigned short*)(smem + 16384);  // [64][128]
  unsigned short* sMs  = (unsigned short*)(smem + 16384);  // alias: [64][72]
  unsigned short* sBsT = (unsigned short*)(smem + 32768);  // [128][72] scaled B^T
  unsigned short* sXsT = (unsigned short*)(smem + 51200);  // [64][72]  x^T
  float* sdt = (float*)(smem + 60416);
  float* sdl = (float*)(smem + 60672);

  const int bi = blockIdx.x;
  const int ch = bi & 31, h = (bi >> 5) & 63, b = bi >> 11;
  const int bh = b * NH + h;
  const int tok0 = b * LSEQ + ch * QC;
  const int t = threadIdx.x;
  const int w = t >> 6, l = t & 63, lr = l & 15, hi = l >> 4;
  const float Ah = -__expf(A_log[h]);
  const float Dh = Dv[h];

  {
    const int srow = t >> 4, scol = (t & 15) * 8;
#pragma unroll
    for (int i = 0; i < 4; i++) {
      const unsigned short* gb = bcbf + (size_t)(tok0 + srow + 16 * i) * 256 + scol;
      GLL(gb, (char*)sBs + i * 4096 + w * 1024);
      GLL(gb + 128, (char*)sCs + i * 4096 + w * 1024);
    }
  }
  if (t < QC) sdt[t] = dtg[(size_t)(tok0 + t) * NH + h];
  __syncthreads();
  if (t < QC) sdl[t] = sdt[t];
  __syncthreads();
  for (int off = 1; off < QC; off <<= 1) {
    float v = 0.f;
    if (t < QC && t >= off) v = sdl[t - off];
    __syncthreads();
    if (t < QC) sdl[t] += v;
    __syncthreads();
  }

  {
    const int s = t >> 2;
    const float DlQ = sdl[QC - 1];
    const float csc = __expf(Ah * (DlQ - sdl[s])) * sdt[s];
    const int n0 = (t & 3) * 32;
#pragma unroll
    for (int j = 0; j < 32; j++) {
      float bv = bf2f(sBs[s * 128 + n0 + j]);
      sBsT[(n0 + j) * 72 + s] = f2bf(csc * bv);
    }
    const int p0 = (t & 3) * 16;
    const unsigned short* gx = xbf + (size_t)(tok0 + s) * DI + h * 64 + p0;
    union { uint4 v; unsigned short u[8]; } x0, x1;
    x0.v = *(const uint4*)gx;
    x1.v = *(const uint4*)(gx + 8);
#pragma unroll
    for (int j = 0; j < 8; j++) {
      sXsT[(p0 + j) * 72 + s] = x0.u[j];
      sXsT[(p0 + 8 + j) * 72 + s] = x1.u[j];
    }
  }
  __syncthreads();

  f32x4 accS[4];
#pragma unroll
  for (int jf = 0; jf < 4; jf++) accS[jf] = (f32x4){0.f, 0.f, 0.f, 0.f};
#pragma unroll
  for (int ks = 0; ks < 4; ks++) {
    bf16x8 a = *(const bf16x8*)&sBs[(w * 16 + lr) * 128 + ks * 32 + hi * 8];
#pragma unroll
    for (int jf = 0; jf < 4; jf++) {
      bf16x8 bbq = *(const bf16x8*)&sCs[(jf * 16 + lr) * 128 + ks * 32 + hi * 8];
      accS[jf] = __builtin_amdgcn_mfma_f32_16x16x32_bf16(a, bbq, accS[jf], 0, 0, 0);
    }
  }
  __syncthreads();

  {
    const int s0 = w * 16 + hi * 4;
#pragma unroll
    for (int jf = 0; jf < 4; jf++) {
      const int tt = jf * 16 + lr;
      const float dlt = sdl[tt];
      unsigned short mv[4];
#pragma unroll
      for (int r = 0; r < 4; r++) {
        const int ss = s0 + r;
        float val = 0.f;
        if (ss <= tt) val = accS[jf][r] * __expf(Ah * (dlt - sdl[ss])) * sdt[ss];
        mv[r] = f2bf(val);
      }
      *(ushort4*)&sMs[tt * 72 + s0] = *(ushort4*)mv;
    }
  }
  __syncthreads();

  {
    f32x4 accY[4];
#pragma unroll
    for (int jf = 0; jf < 4; jf++) accY[jf] = (f32x4){0.f, 0.f, 0.f, 0.f};
#pragma unroll
    for (int ks = 0; ks < 2; ks++) {
      bf16x8 a = *(const bf16x8*)&sMs[(w * 16 + lr) * 72 + ks * 32 + hi * 8];
#pragma unroll
      for (int jf = 0; jf < 4; jf++) {
        bf16x8 bbq = *(const bf16x8*)&sXsT[(jf * 16 + lr) * 72 + ks * 32 + hi * 8];
        accY[jf] = __builtin_amdgcn_mfma_f32_16x16x32_bf16(a, bbq, accY[jf], 0, 0, 0);
      }
    }
#pragma unroll
    for (int jf = 0; jf < 4; jf++)
#pragma unroll
      for (int r = 0; r < 4; r++) {
        const int tt = w * 16 + hi * 4 + r;
        const int pp = jf * 16 + lr;
        float xv = bf2f(sXsT[pp * 72 + tt]);
        ybuf[(size_t)(tok0 + tt) * DI + h * 64 + pp] = f2bf(accY[jf][r] + Dh * xv);
      }
  }

  {
    f32x4 accT[8];
#pragma unroll
    for (int jf = 0; jf < 8; jf++) accT[jf] = (f32x4){0.f, 0.f, 0.f, 0.f};
#pragma unroll
    for (int ks = 0; ks < 2; ks++) {
      bf16x8 a = *(const bf16x8*)&sXsT[(w * 16 + lr) * 72 + ks * 32 + hi * 8];
#pragma unroll
      for (int jf = 0; jf < 8; jf++) {
        bf16x8 bbq = *(const bf16x8*)&sBsT[(jf * 16 + lr) * 72 + ks * 32 + hi * 8];
        accT[jf] = __builtin_amdgcn_mfma_f32_16x16x32_bf16(a, bbq, accT[jf], 0, 0, 0);
      }
    }
    unsigned short* sc = Sc + ((size_t)bh * NCH + ch) * (PDIM * NSTATE);
#pragma unroll
    for (int jf = 0; jf < 8; jf++)
#pragma unroll
      for (int r = 0; r < 4; r++) {
        const int pp = w * 16 + hi * 4 + r;
        const int nn = jf * 16 + lr;
        sc[pp * NSTATE + nn] = f2bf(accT[jf][r]);
      }
  }
  if (t == 0) dtsum[bh * NCH + ch] = sdl[QC - 1];
}

// ---------------- SSD kernel 2: serial chunk-state combine ----------------
__global__ __launch_bounds__(256)
void k_ssd2(const float* __restrict__ A_log, const float* __restrict__ dtsum,
            unsigned short* __restrict__ ScHt) {
  const int blk = blockIdx.x;
  const int bh = blk >> 3, pg = blk & 7;
  const int t = threadIdx.x;
  const int p = pg * 8 + (t >> 5), n0 = (t & 31) * 4;
  const int h = bh & 63;
  const float Ah = -__expf(A_log[h]);
  float H[4] = {0.f, 0.f, 0.f, 0.f};
  for (int c = 0; c < NCH; c++) {
    size_t base = (((size_t)bh * NCH + c) * PDIM + p) * NSTATE + n0;
    ushort4 sv = *(const ushort4*)&ScHt[base];
    float dec = __expf(Ah * dtsum[bh * NCH + c]);
    ushort4 hv;
    hv.x = f2bf(H[0]); hv.y = f2bf(H[1]); hv.z = f2bf(H[2]); hv.w = f2bf(H[3]);
    *(ushort4*)&ScHt[base] = hv;
    H[0] = dec * H[0] + bf2f(sv.x);
    H[1] = dec * H[1] + bf2f(sv.y);
    H[2] = dec * H[2] + bf2f(sv.z);
    H[3] = dec * H[3] + bf2f(sv.w);
  }
}

// ---------------- SSD kernel 3: inter-chunk Y += decay * C @ H_in ----------------
__global__ __launch_bounds__(256)
void k_ssd3(const unsigned short* __restrict__ bcbf, const unsigned short* __restrict__ Ht,
            const float* __restrict__ dtg, const float* __restrict__ A_log,
            unsigned short* __restrict__ ybuf) {
  __shared__ __align__(16) char smem[33280];
  unsigned short* sCs = (unsigned short*)(smem);
  unsigned short* sHt = (unsigned short*)(smem + 16384);
  float* sdt = (float*)(smem + 32768);
  float* sdl = (float*)(smem + 33024);

  const int bi = blockIdx.x;
  const int ch = bi & 31, h = (bi >> 5) & 63, b = bi >> 11;
  const int bh = b * NH + h;
  const int tok0 = b * LSEQ + ch * QC;
  const int t = threadIdx.x;
  const int w = t >> 6, l = t & 63, lr = l & 15, hi = l >> 4;
  const float Ah = -__expf(A_log[h]);

  {
    const int srow = t >> 4, scol = (t & 15) * 8;
    const unsigned short* gh = Ht + ((size_t)bh * NCH + ch) * (PDIM * NSTATE);
#pragma unroll
    for (int i = 0; i < 4; i++) {
      const unsigned short* gc = bcbf + (size_t)(tok0 + srow + 16 * i) * 256 + 128 + scol;
      GLL(gc, (char*)sCs + i * 4096 + w * 1024);
      GLL(gh + i * 2048 + t * 8, (char*)sHt + i * 4096 + w * 1024);
    }
  }
  if (t < QC) sdt[t] = dtg[(size_t)(tok0 + t) * NH + h];
  __syncthreads();
  if (t < QC) sdl[t] = sdt[t];
  __syncthreads();
  for (int off = 1; off < QC; off <<= 1) {
    float v = 0.f;
    if (t < QC && t >= off) v = sdl[t - off];
    __syncthreads();
    if (t < QC) sdl[t] += v;
    __syncthreads();
  }

  f32x4 acc[4];
#pragma unroll
  for (int jf = 0; jf < 4; jf++) acc[jf] = (f32x4){0.f, 0.f, 0.f, 0.f};
#pragma unroll
  for (int ks = 0; ks < 4; ks++) {
    bf16x8 a = *(const bf16x8*)&sCs[(w * 16 + lr) * 128 + ks * 32 + hi * 8];
#pragma unroll
    for (int jf = 0; jf < 4; jf++) {
      bf16x8 bbq = *(const bf16x8*)&sHt[(jf * 16 + lr) * 128 + ks * 32 + hi * 8];
      acc[jf] = __builtin_amdgcn_mfma_f32_16x16x32_bf16(a, bbq, acc[jf], 0, 0, 0);
    }
  }
#pragma unroll
  for (int jf = 0; jf < 4; jf++)
#pragma unroll
    for (int r = 0; r < 4; r++) {
      const int tt = w * 16 + hi * 4 + r;
      const int pp = jf * 16 + lr;
      const float dec = __expf(Ah * sdl[tt]);
      const size_t o = (size_t)(tok0 + tt) * DI + h * 64 + pp;
      ybuf[o] = f2bf(bf2f(ybuf[o]) + dec * acc[jf][r]);
    }
}

// ---------------- workspace layout (bytes), total ~412.1 MB ----------------
static const size_t OFF_WBF_IN  = 0;            // 8704*2048*2  = 35651584
static const size_t OFF_WBF_OUT = 35651584;     // 2048*4096*2  = 16777216
static const size_t OFF_WBF_GU  = 52428800;     // 16384*2048*2 = 67108864
static const size_t OFF_WBF_DN  = 119537664;    // 2048*8192*2  = 33554432
static const size_t OFF_RESID   = 153092096;    // 4096*2048*4  = 33554432
static const size_t OFF_HSBF    = 186646528;    // 4096*2048*2  = 16777216
static const size_t OFF_PROJ    = 203423744;    // 4096*8704*2  = 71303168 (alias actbf)
static const size_t OFF_XBF     = 274726912;    // 4096*4096*2  = 33554432 (alias ynorm)
static const size_t OFF_BCBF    = 308281344;    // 4096*256*2   = 2097152
static const size_t OFF_DTG     = 310378496;    // 4096*64*4    = 1048576
static const size_t OFF_YBUF    = 311427072;    // 4096*4096*2  = 33554432
static const size_t OFF_SC      = 344981504;    // 128*32*64*128*2 = 67108864
static const size_t OFF_DTSUM   = 412090368;    // f32 [128][32]

extern "C" void kernel_launch(void* const* d_in, const int* in_sizes, int n_in,
                              void* d_out, int out_size, void* d_ws, size_t ws_size,
                              hipStream_t stream) {
  (void)in_sizes; (void)n_in; (void)out_size; (void)ws_size;
  const float* hidden   = (const float*)d_in[1];
  const float* resin    = (const float*)d_in[2];
  const float* w_inproj = (const float*)d_in[3];
  const float* conv_w   = (const float*)d_in[4];
  const float* conv_b   = (const float*)d_in[5];
  const float* A_log    = (const float*)d_in[6];
  const float* Dvec     = (const float*)d_in[7];
  const float* dt_bias  = (const float*)d_in[8];
  const float* w_mix    = (const float*)d_in[9];
  const float* w_outp   = (const float*)d_in[10];
  const float* w_ln1    = (const float*)d_in[11];
  const float* w_ln2    = (const float*)d_in[12];
  const float* w_gu     = (const float*)d_in[13];
  const float* w_dn     = (const float*)d_in[14];

  char* ws = (char*)d_ws;
  unsigned short* wbf_in  = (unsigned short*)(ws + OFF_WBF_IN);
  unsigned short* wbf_out = (unsigned short*)(ws + OFF_WBF_OUT);
  unsigned short* wbf_gu  = (unsigned short*)(ws + OFF_WBF_GU);
  unsigned short* wbf_dn  = (unsigned short*)(ws + OFF_WBF_DN);
  float*          residb  = (float*)(ws + OFF_RESID);
  unsigned short* hsbf    = (unsigned short*)(ws + OFF_HSBF);
  unsigned short* projbf  = (unsigned short*)(ws + OFF_PROJ);
  unsigned short* actbf   = (unsigned short*)(ws + OFF_PROJ);   // alias
  unsigned short* xbf     = (unsigned short*)(ws + OFF_XBF);
  unsigned short* ynormbf = (unsigned short*)(ws + OFF_XBF);    // alias
  unsigned short* bcbf    = (unsigned short*)(ws + OFF_BCBF);
  float*          dtgb    = (float*)(ws + OFF_DTG);
  unsigned short* ybuf    = (unsigned short*)(ws + OFF_YBUF);
  unsigned short* scht    = (unsigned short*)(ws + OFF_SC);
  float*          dtsumb  = (float*)(ws + OFF_DTSUM);

  float* out0 = (float*)d_out;
  float* res2 = out0 + (size_t)T_TOK * HID;

  // 0) all weight conversions in one kernel
  k_cvt_all<<<37376, 256, 0, stream>>>(w_inproj, w_outp, w_gu, w_dn,
                                       wbf_in, wbf_out, wbf_gu, wbf_dn);
  // 1) residual add + input rmsnorm
  k_addnorm<<<T_TOK, 256, 0, stream>>>(hidden, resin, w_ln1, residb, hsbf);
  // 2) in_proj GEMM -> proj bf16 [4096][8704]; grid 34*32 = 1088
  gemmk<0><<<34 * 32, 512, 0, stream>>>(hsbf, wbf_in, HID, DPADR, projbf, nullptr);
  // 3) causal conv + silu -> xbf / bcbf (bf16), fused dt softplus
  k_conv<<<dim3(18, T_TOK), 256, 0, stream>>>(projbf, conv_w, conv_b, dt_bias, xbf, bcbf, dtgb);
  // 4) SSD intra + chunk states
  k_ssd1<<<4096, 256, 0, stream>>>(xbf, bcbf, dtgb, A_log, Dvec, ybuf, scht, dtsumb);
  // 5) SSD serial combine
  k_ssd2<<<1024, 256, 0, stream>>>(A_log, dtsumb, scht);
  // 6) SSD inter-chunk
  k_ssd3<<<4096, 256, 0, stream>>>(bcbf, scht, dtgb, A_log, ybuf);
  // 7) gate + mixer rmsnorm -> ynorm bf16
  k_gatenorm<<<T_TOK, 256, 0, stream>>>(ybuf, projbf, w_mix, ynormbf);
  // 8) out_proj GEMM + residual -> residual2 (output 1); grid 8*32 = 256
  gemmk<1><<<8 * 32, 512, 0, stream>>>(ynormbf, wbf_out, DI, HID, res2, residb);
  // 9) pre-FF rmsnorm -> hs2 bf16
  k_rmsnorm_bf<<<T_TOK, 256, 0, stream>>>(res2, w_ln2, hsbf);
  // 10) gate_up GEMM (fused silu-pair epilogue) -> act bf16; grid 64*32 = 2048
  gemmk<2><<<64 * 32, 512, 0, stream>>>(hsbf, wbf_gu, HID, IM, actbf, nullptr);
  // 11) down GEMM -> out (output 0); grid 8*32 = 256
  gemmk<3><<<8 * 32, 512, 0, stream>>>(actbf, wbf_dn, IM, HID, out0, nullptr);
}

// Round 10
// 1027.352 us; speedup vs baseline: 1.0930x; 1.0930x over previous
//
#include <hip/hip_runtime.h>

// ---------------- problem constants ----------------
#define T_TOK 4096          // BB*L tokens
#define HID   2048
#define DI    4096
#define NH    64
#define PDIM  64
#define NSTATE 128
#define IM    8192
#define LSEQ  2048
#define CONVD 4352          // DI + 2*G*N
#define DPROJ 8512          // 2*DI + 2*G*N + NH
#define DPADR 8704          // padded to 34*256
#define QC    64            // SSD chunk length
#define NCH   32            // chunks per sequence

typedef __bf16 bf16x8 __attribute__((ext_vector_type(8)));
typedef float  f32x4  __attribute__((ext_vector_type(4)));

__device__ __forceinline__ unsigned short f2bf(float f) {
  unsigned u = __float_as_uint(f);
  u = (u + 0x7fffu + ((u >> 16) & 1u)) >> 16;
  return (unsigned short)u;
}
__device__ __forceinline__ float bf2f(unsigned short h) {
  return __uint_as_float(((unsigned)h) << 16);
}
__device__ __forceinline__ float siluf(float x) {
  return x / (1.f + __expf(-x));
}

#define GLL(gaddr, laddr) __builtin_amdgcn_global_load_lds( \
    (const __attribute__((address_space(1))) void*)(gaddr), \
    (__attribute__((address_space(3))) void*)(laddr), 16, 0, 0)

// ---------------- merged weight conversion ----------------
__device__ __forceinline__ void cvt8(const float* __restrict__ s, unsigned short* __restrict__ d) {
  float4 v0 = *(const float4*)s;
  float4 v1 = *(const float4*)(s + 4);
  unsigned short o[8];
  o[0] = f2bf(v0.x); o[1] = f2bf(v0.y); o[2] = f2bf(v0.z); o[3] = f2bf(v0.w);
  o[4] = f2bf(v1.x); o[5] = f2bf(v1.y); o[6] = f2bf(v1.z); o[7] = f2bf(v1.w);
  *(uint4*)d = *(const uint4*)o;
}

#define CV_IN_END  2228224ULL
#define CV_OUT_END 3276800ULL
#define CV_GU_END  7471104ULL
#define CV_DN_END  9568256ULL

__global__ __launch_bounds__(256)
void k_cvt_all(const float* __restrict__ w_in, const float* __restrict__ w_out,
               const float* __restrict__ w_gu, const float* __restrict__ w_dn,
               unsigned short* __restrict__ d_in, unsigned short* __restrict__ d_out,
               unsigned short* __restrict__ d_gu, unsigned short* __restrict__ d_dn) {
  size_t gid = (size_t)blockIdx.x * 256 + threadIdx.x;
  if (gid < CV_IN_END) {
    size_t idx8 = gid * 8;
    int r = (int)(idx8 >> 11), k = (int)(idx8 & 2047);
    if (r < DPROJ) {
      cvt8(&w_in[(size_t)r * HID + k], d_in + idx8);
    } else {
      uint4 z = {0, 0, 0, 0};
      *(uint4*)(d_in + idx8) = z;
    }
  } else if (gid < CV_OUT_END) {
    size_t idx8 = (gid - CV_IN_END) * 8;
    cvt8(w_out + idx8, d_out + idx8);
  } else if (gid < CV_GU_END) {
    size_t idx8 = (gid - CV_OUT_END) * 8;
    int r = (int)(idx8 >> 11), k = (int)(idx8 & 2047);
    int g = r >> 6, j = r & 63;
    int srcr = (j < 32) ? (g * 32 + j) : (IM + g * 32 + (j - 32));
    cvt8(&w_gu[(size_t)srcr * HID + k], d_gu + idx8);
  } else if (gid < CV_DN_END) {
    size_t idx8 = (gid - CV_GU_END) * 8;
    cvt8(w_dn + idx8, d_dn + idx8);
  }
}

// ---------------- 8-phase 256x256x64 GEMM (m201-style, counted vmcnt) ----------------
// Same addressing/swizzle as the proven R5/R8 kernel; only the schedule changed.
// LDS: 2 bufs x {A 32KB (2 halves), B 32KB (2 halves)}. Iter = 2 K-tiles:
// group g=0 computes T0 from buf0 (4 quadrant phases), g=1 computes T0+1 from buf1.
// Stage exactly ONE 16KB unit per phase:
//   p1: buf1.A0<-T0+1  p2: buf1.A1<-T0+1  p3: buf0.B0<-T0+2  p4: buf0.B1<-T0+2 +vmcnt(4)
//   p5: buf0.A0<-T0+2  p6: buf0.A1<-T0+2  p7: buf1.B0<-T0+3  p8: buf1.B1<-T0+3 +vmcnt(4)
// Hazards verified: every unit covered by a counted vmcnt >=1 phase before first read;
// every slot rewritten >=1 barrier after its last read. Final-iter waits drop to vmcnt(0).
template <int EPI>
__global__ __launch_bounds__(512, 1)
void gemm8p(const unsigned short* __restrict__ A, const unsigned short* __restrict__ W,
            int K, int ldo, void* __restrict__ outp) {
  __shared__ __align__(16) char smem[131072];
  const int t = threadIdx.x;
  const int w = t >> 6, l = t & 63;
  const int lr = l & 15, hi = l >> 4;
  const int wr = w >> 2, wc = w & 3;

  // T1: bijective XCD swizzle over tn-major enumeration (grid % 8 == 0)
  const int q8 = (int)gridDim.x >> 3;
  const int bid = blockIdx.x;
  const int id2 = (bid & 7) * q8 + (bid >> 3);
  const int tn = id2 >> 4, tm = id2 & 15;
  const int m0b = tm << 8, n0b = tn << 8;

  // staging lane constants; source col pre-swizzled (byte bits 5,6 <- row bits 2,3)
  const int srow = t >> 3;
  const int scole = ((t & 7) << 3) ^ ((t & 32) ? 16 : 0) ^ ((t & 64) ? 32 : 0);
  const unsigned short* Ag = A + (size_t)(m0b + srow) * K + scole;
  const unsigned short* Wg = W + (size_t)(n0b + srow) * K + scole;
  const int ldsw = w * 1024;

  // ds_read swizzled byte bases per kk (verbatim from proven kernel)
  const int fa = ((lr & 4) ? 32 : 0) | ((lr & 8) ? 64 : 0);
  const int arow = (wr * 128 + lr) * 128 + hi * 16;
  const int brow = (wc * 64 + lr) * 128 + hi * 16;
  const int aoff0 = arow ^ fa, aoff1 = (arow + 64) ^ fa;
  const int boff0 = brow ^ fa, boff1 = (brow + 64) ^ fa;

  // stage one 16KB unit: matrix half h (rows h*128..h*128+127) of K-tile jt
#define STAGE_A(jt, h, bb) do {                                                 \
    _Pragma("unroll")                                                           \
    for (int p_ = 0; p_ < 2; ++p_)                                              \
      GLL(Ag + (size_t)((h) * 128 + p_ * 64) * K + (size_t)(jt) * 64,           \
          smem + (bb) * 65536 + ((h) * 2 + p_) * 8192 + ldsw); } while (0)
#define STAGE_B(jt, h, bb) do {                                                 \
    _Pragma("unroll")                                                           \
    for (int p_ = 0; p_ < 2; ++p_)                                              \
      GLL(Wg + (size_t)((h) * 128 + p_ * 64) * K + (size_t)(jt) * 64,           \
          smem + (bb) * 65536 + 32768 + ((h) * 2 + p_) * 8192 + ldsw); } while (0)

#define RDF(off, base) (*(const bf16x8*)((base) + (off)))

  f32x4 acc[8][4];
#pragma unroll
  for (int m = 0; m < 8; m++)
#pragma unroll
    for (int n = 0; n < 4; n++) acc[m][n] = (f32x4){0.f, 0.f, 0.f, 0.f};

  const int nkt = K >> 6;       // 32 (even)
  const int niter = nkt >> 1;

  // prologue: T0 all 4 units -> buf0; T1's B units -> buf1
  STAGE_A(0, 0, 0); STAGE_A(0, 1, 0);
  STAGE_B(0, 0, 0); STAGE_B(0, 1, 0);
  STAGE_B(1, 0, 1); STAGE_B(1, 1, 1);
  asm volatile("s_waitcnt vmcnt(4)" ::: "memory");   // T0 units landed; T1.B in flight
  __builtin_amdgcn_s_barrier();
  __builtin_amdgcn_sched_barrier(0);

  for (int it = 0; it < niter; ++it) {
    const int T0 = 2 * it;
#pragma unroll
    for (int g = 0; g < 2; ++g) {
      const char* Ab = smem + g * 65536;
      const char* Bb = Ab + 32768;
      bf16x8 bfr[8];
#pragma unroll
      for (int q = 0; q < 4; ++q) {
        // ---- reads for this quadrant (current buffer; resident & covered) ----
        if (q == 0) {
#pragma unroll
          for (int n = 0; n < 4; n++) {
            bfr[n]     = RDF(boff0 + n * 2048, Bb);
            bfr[4 + n] = RDF(boff1 + n * 2048, Bb);
          }
        }
        bf16x8 a0 = RDF(aoff0 + (2 * q) * 2048, Ab);
        bf16x8 a1 = RDF(aoff0 + (2 * q + 1) * 2048, Ab);
        bf16x8 a2 = RDF(aoff1 + (2 * q) * 2048, Ab);
        bf16x8 a3 = RDF(aoff1 + (2 * q + 1) * 2048, Ab);
        // ---- stage exactly one unit (WAR-safe slots per schedule) ----
        if (g == 0) {
          if (q == 0)      STAGE_A(T0 + 1, 0, 1);
          else if (q == 1) STAGE_A(T0 + 1, 1, 1);
          else if (q == 2) { if (T0 + 2 < nkt) STAGE_B(T0 + 2, 0, 0); }
          else             { if (T0 + 2 < nkt) STAGE_B(T0 + 2, 1, 0); }
        } else {
          if (q == 0)      { if (T0 + 2 < nkt) STAGE_A(T0 + 2, 0, 0); }
          else if (q == 1) { if (T0 + 2 < nkt) STAGE_A(T0 + 2, 1, 0); }
          else if (q == 2) { if (T0 + 3 < nkt) STAGE_B(T0 + 3, 0, 1); }
          else             { if (T0 + 3 < nkt) STAGE_B(T0 + 3, 1, 1); }
        }
        __builtin_amdgcn_sched_barrier(0);
        __builtin_amdgcn_s_barrier();
        __builtin_amdgcn_sched_barrier(0);
        // ---- 16 MFMA (compiler inserts lgkmcnt waits on a*/bfr deps) ----
        __builtin_amdgcn_s_setprio(1);
#pragma unroll
        for (int n = 0; n < 4; n++) {
          acc[2 * q][n]     = __builtin_amdgcn_mfma_f32_16x16x32_bf16(a0, bfr[n], acc[2 * q][n], 0, 0, 0);
          acc[2 * q + 1][n] = __builtin_amdgcn_mfma_f32_16x16x32_bf16(a1, bfr[n], acc[2 * q + 1][n], 0, 0, 0);
        }
#pragma unroll
        for (int n = 0; n < 4; n++) {
          acc[2 * q][n]     = __builtin_amdgcn_mfma_f32_16x16x32_bf16(a2, bfr[4 + n], acc[2 * q][n], 0, 0, 0);
          acc[2 * q + 1][n] = __builtin_amdgcn_mfma_f32_16x16x32_bf16(a3, bfr[4 + n], acc[2 * q + 1][n], 0, 0, 0);
        }
        __builtin_amdgcn_s_setprio(0);
        __builtin_amdgcn_sched_barrier(0);
        // ---- end of phase: counted wait once per K-tile ----
        if (q == 3) {
          const int lastStaged = (g == 0) ? (T0 + 2) : (T0 + 3);
          if (lastStaged < nkt) asm volatile("s_waitcnt vmcnt(4)" ::: "memory");
          else                  asm volatile("s_waitcnt vmcnt(0)" ::: "memory");
        }
        __builtin_amdgcn_s_barrier();
        __builtin_amdgcn_sched_barrier(0);
      }
    }
  }

  if constexpr (EPI == 0) {
    unsigned short* op = (unsigned short*)outp;
#pragma unroll
    for (int m = 0; m < 8; m++)
#pragma unroll
      for (int n = 0; n < 4; n++)
#pragma unroll
        for (int r = 0; r < 4; r++) {
          int row = m0b + wr * 128 + m * 16 + hi * 4 + r;
          int col = n0b + wc * 64 + n * 16 + lr;
          op[(size_t)row * ldo + col] = f2bf(acc[m][n][r]);
        }
  } else {  // EPI == 2: gate-pair silu
    unsigned short* op = (unsigned short*)outp;
    const int gbase = (n0b + wc * 64) >> 1;
#pragma unroll
    for (int m = 0; m < 8; m++)
#pragma unroll
      for (int n = 0; n < 2; n++)
#pragma unroll
        for (int r = 0; r < 4; r++) {
          int row = m0b + wr * 128 + m * 16 + hi * 4 + r;
          int col = gbase + n * 16 + lr;
          float gg = acc[m][n][r], u = acc[m][n + 2][r];
          op[(size_t)row * ldo + col] = f2bf(siluf(gg) * u);
        }
  }
#undef STAGE_A
#undef STAGE_B
#undef RDF
}

// ---------------- R5-style pipelined 128x256 GEMM (out_proj / down) ----------------
template <int EPI, int BM>
__global__ __launch_bounds__(512, 2)
void gemm8(const unsigned short* __restrict__ A, const unsigned short* __restrict__ W,
           int K, int ldo, void* __restrict__ outp,
           const float* __restrict__ resid) {
  constexpr int MREP  = BM / 32;
  constexpr int ABYT  = BM * 128;
  constexpr int BUFB  = ABYT + 32768;
  constexpr int NTM   = 4096 / BM;
  __shared__ __align__(16) char smem[2 * BUFB];
  const int t = threadIdx.x;
  const int w = t >> 6, l = t & 63;
  const int lr = l & 15, hi = l >> 4;
  const int wr = w >> 2, wc = w & 3;

  const int q = (int)gridDim.x >> 3;
  const int bid = blockIdx.x;
  const int id2 = (bid & 7) * q + (bid >> 3);
  const int tn = id2 / NTM, tm = id2 % NTM;
  const int m0b = tm * BM, n0b = tn << 8;

  const int srow = t >> 3;
  const int scole = ((t & 7) << 3) ^ ((t & 32) ? 16 : 0) ^ ((t & 64) ? 32 : 0);
  const unsigned short* Ag = A + (size_t)(m0b + srow) * K + scole;
  const unsigned short* Wg = W + (size_t)(n0b + srow) * K + scole;
  const int ldsw = w * 1024;

  const int fa = ((lr & 4) ? 32 : 0) | ((lr & 8) ? 64 : 0);
  const int arow = (wr * (BM / 2) + lr) * 128 + hi * 16;
  const int brow = (wc * 64 + lr) * 128 + hi * 16;
  const int aoff0 = arow ^ fa, aoff1 = (arow + 64) ^ fa;
  const int boff0 = brow ^ fa, boff1 = (brow + 64) ^ fa;

#define ISSUE_A(jt, bb) do {                                                    \
    _Pragma("unroll")                                                           \
    for (int p_ = 0; p_ < BM / 64; ++p_)                                        \
      GLL(Ag + (size_t)(p_ * 64) * K + (size_t)(jt) * 64,                       \
          smem + (bb) * BUFB + p_ * 8192 + ldsw); } while (0)
#define ISSUE_B(jt, bb) do {                                                    \
    _Pragma("unroll")                                                           \
    for (int p_ = 0; p_ < 4; ++p_)                                              \
      GLL(Wg + (size_t)(p_ * 64) * K + (size_t)(jt) * 64,                       \
          smem + (bb) * BUFB + ABYT + p_ * 8192 + ldsw); } while (0)

#define RDF(off, base) (*(const bf16x8*)((base) + (off)))
#define MF(P, x, y, c0, c1, c2, c3) do {                                                     \
    __builtin_amdgcn_s_setprio(1);                                                           \
    acc[2*(P)  ][0] = __builtin_amdgcn_mfma_f32_16x16x32_bf16((x),(c0),acc[2*(P)  ][0],0,0,0);\
    acc[2*(P)+1][0] = __builtin_amdgcn_mfma_f32_16x16x32_bf16((y),(c0),acc[2*(P)+1][0],0,0,0);\
    acc[2*(P)  ][1] = __builtin_amdgcn_mfma_f32_16x16x32_bf16((x),(c1),acc[2*(P)  ][1],0,0,0);\
    acc[2*(P)+1][1] = __builtin_amdgcn_mfma_f32_16x16x32_bf16((y),(c1),acc[2*(P)+1][1],0,0,0);\
    acc[2*(P)  ][2] = __builtin_amdgcn_mfma_f32_16x16x32_bf16((x),(c2),acc[2*(P)  ][2],0,0,0);\
    acc[2*(P)+1][2] = __builtin_amdgcn_mfma_f32_16x16x32_bf16((y),(c2),acc[2*(P)+1][2],0,0,0);\
    acc[2*(P)  ][3] = __builtin_amdgcn_mfma_f32_16x16x32_bf16((x),(c3),acc[2*(P)  ][3],0,0,0);\
    acc[2*(P)+1][3] = __builtin_amdgcn_mfma_f32_16x16x32_bf16((y),(c3),acc[2*(P)+1][3],0,0,0);\
    __builtin_amdgcn_s_setprio(0); } while (0)

  f32x4 acc[MREP][4];
#pragma unroll
  for (int m = 0; m < MREP; m++)
#pragma unroll
    for (int n = 0; n < 4; n++) acc[m][n] = (f32x4){0.f, 0.f, 0.f, 0.f};

  const int nkt = K >> 6;
  ISSUE_A(0, 0); ISSUE_B(0, 0);

  for (int j = 0; j < nkt; ++j) {
    const int cur = j & 1;
    const char* Ab = smem + cur * BUFB;
    const char* Bb = Ab + ABYT;
    asm volatile("s_waitcnt vmcnt(0)" ::: "memory");
    __builtin_amdgcn_s_barrier();
    __builtin_amdgcn_sched_barrier(0);
    if (j + 1 < nkt) { ISSUE_A(j + 1, cur ^ 1); ISSUE_B(j + 1, cur ^ 1); }
    bf16x8 b0 = RDF(boff0, Bb), b1 = RDF(boff0 + 2048, Bb),
           b2 = RDF(boff0 + 4096, Bb), b3 = RDF(boff0 + 6144, Bb);
    bf16x8 af0 = RDF(aoff0, Ab), af1 = RDF(aoff0 + 2048, Ab);
    bf16x8 af2, af3, b4, b5, b6, b7;
    af2 = RDF(aoff0 + 4096, Ab); af3 = RDF(aoff0 + 6144, Ab);
    MF(0, af0, af1, b0, b1, b2, b3);
    b4 = RDF(boff1, Bb); b5 = RDF(boff1 + 2048, Bb);
    b6 = RDF(boff1 + 4096, Bb); b7 = RDF(boff1 + 6144, Bb);
    af0 = RDF(aoff1, Ab); af1 = RDF(aoff1 + 2048, Ab);
    MF(1, af2, af3, b0, b1, b2, b3);
    af2 = RDF(aoff1 + 4096, Ab); af3 = RDF(aoff1 + 6144, Ab);
    MF(0, af0, af1, b4, b5, b6, b7);
    MF(1, af2, af3, b4, b5, b6, b7);
  }

#pragma unroll
  for (int m = 0; m < MREP; m++)
#pragma unroll
    for (int n = 0; n < 4; n++)
#pragma unroll
      for (int r = 0; r < 4; r++) {
        int row = m0b + wr * (BM / 2) + m * 16 + hi * 4 + r;
        int col = n0b + wc * 64 + n * 16 + lr;
        float v = acc[m][n][r];
        if constexpr (EPI == 1) {
          ((float*)outp)[(size_t)row * ldo + col] = v + resid[(size_t)row * ldo + col];
        } else {
          ((float*)outp)[(size_t)row * ldo + col] = v;
        }
      }
#undef ISSUE_A
#undef ISSUE_B
#undef RDF
#undef MF
}

// ---------------- norms ----------------
__device__ __forceinline__ float block_reduce_sum256(float v, float* sred) {
#pragma unroll
  for (int m = 32; m; m >>= 1) v += __shfl_xor(v, m);
  int t = threadIdx.x;
  if ((t & 63) == 0) sred[t >> 6] = v;
  __syncthreads();
  return sred[0] + sred[1] + sred[2] + sred[3];
}

__global__ __launch_bounds__(256)
void k_addnorm(const float* __restrict__ hin, const float* __restrict__ rin,
               const float* __restrict__ wln, float* __restrict__ rout,
               unsigned short* __restrict__ hbf) {
  __shared__ float sred[4];
  const int tok = blockIdx.x, t = threadIdx.x;
  const size_t base = (size_t)tok * HID + t * 8;
  float4 a0 = *(const float4*)&hin[base];
  float4 a1 = *(const float4*)&hin[base + 4];
  float4 b0 = *(const float4*)&rin[base];
  float4 b1 = *(const float4*)&rin[base + 4];
  float v[8] = {a0.x + b0.x, a0.y + b0.y, a0.z + b0.z, a0.w + b0.w,
                a1.x + b1.x, a1.y + b1.y, a1.z + b1.z, a1.w + b1.w};
  float ss = 0.f;
#pragma unroll
  for (int j = 0; j < 8; j++) ss += v[j] * v[j];
  float tot = block_reduce_sum256(ss, sred);
  float rms = rsqrtf(tot * (1.f / HID) + 1e-5f);
  *(float4*)&rout[base] = (float4){v[0], v[1], v[2], v[3]};
  *(float4*)&rout[base + 4] = (float4){v[4], v[5], v[6], v[7]};
  float4 w0 = *(const float4*)&wln[t * 8];
  float4 w1 = *(const float4*)&wln[t * 8 + 4];
  float wa[8] = {w0.x, w0.y, w0.z, w0.w, w1.x, w1.y, w1.z, w1.w};
  unsigned short o[8];
#pragma unroll
  for (int j = 0; j < 8; j++) o[j] = f2bf(v[j] * rms * wa[j]);
  *(ushort4*)&hbf[base] = *(ushort4*)&o[0];
  *(ushort4*)&hbf[base + 4] = *(ushort4*)&o[4];
}

__global__ __launch_bounds__(256)
void k_rmsnorm_bf(const float* __restrict__ src, const float* __restrict__ wln,
                  unsigned short* __restrict__ dst) {
  __shared__ float sred[4];
  const int tok = blockIdx.x, t = threadIdx.x;
  const size_t base = (size_t)tok * HID + t * 8;
  float4 a0 = *(const float4*)&src[base];
  float4 a1 = *(const float4*)&src[base + 4];
  float v[8] = {a0.x, a0.y, a0.z, a0.w, a1.x, a1.y, a1.z, a1.w};
  float ss = 0.f;
#pragma unroll
  for (int j = 0; j < 8; j++) ss += v[j] * v[j];
  float tot = block_reduce_sum256(ss, sred);
  float rms = rsqrtf(tot * (1.f / HID) + 1e-5f);
  float4 w0 = *(const float4*)&wln[t * 8];
  float4 w1 = *(const float4*)&wln[t * 8 + 4];
  float wa[8] = {w0.x, w0.y, w0.z, w0.w, w1.x, w1.y, w1.z, w1.w};
  unsigned short o[8];
#pragma unroll
  for (int j = 0; j < 8; j++) o[j] = f2bf(v[j] * rms * wa[j]);
  *(ushort4*)&dst[base] = *(ushort4*)&o[0];
  *(ushort4*)&dst[base + 4] = *(ushort4*)&o[4];
}

__global__ __launch_bounds__(256)
void k_gatenorm(const unsigned short* __restrict__ ybuf, const unsigned short* __restrict__ projbf,
                const float* __restrict__ wmix, unsigned short* __restrict__ ynorm) {
  __shared__ float sred[4];
  const int tok = blockIdx.x, t = threadIdx.x;
  const size_t yb = (size_t)tok * DI;
  const size_t pb = (size_t)tok * DPADR;
  float g[16];
  float ss = 0.f;
#pragma unroll
  for (int j = 0; j < 16; j++) {
    int idx = j * 256 + t;
    float yv = bf2f(ybuf[yb + idx]);
    float z = bf2f(projbf[pb + idx]);
    float gg = yv * siluf(z);
    g[j] = gg;
    ss += gg * gg;
  }
  float tot = block_reduce_sum256(ss, sred);
  float rms = rsqrtf(tot * (1.f / DI) + 1e-5f);
#pragma unroll
  for (int j = 0; j < 16; j++) {
    int idx = j * 256 + t;
    ynorm[yb + idx] = f2bf(g[j] * rms * wmix[idx]);
  }
}

// ---------------- conv (depthwise causal K=4) + silu + fused dt softplus ----------------
__global__ __launch_bounds__(256)
void k_conv(const unsigned short* __restrict__ projbf, const float* __restrict__ cw,
            const float* __restrict__ cb, const float* __restrict__ dt_bias,
            unsigned short* __restrict__ xbf, unsigned short* __restrict__ bcbf,
            float* __restrict__ dtg) {
  const int c = blockIdx.x * 256 + threadIdx.x;   // 0..4607
  const int tk = blockIdx.y;                      // token
  if (c < CONVD) {
    const int lpos = tk & (LSEQ - 1);
    float4 wv = *(const float4*)&cw[c * 4];
    float wk[4] = {wv.x, wv.y, wv.z, wv.w};
    float acc = cb[c];
#pragma unroll
    for (int k = 0; k < 4; k++) {
      int lp = lpos - 3 + k;
      if (lp >= 0) acc += bf2f(projbf[(size_t)(tk - 3 + k) * DPADR + DI + c]) * wk[k];
    }
    unsigned short r = f2bf(siluf(acc));
    if (c < DI) xbf[(size_t)tk * DI + c] = r;
    else        bcbf[(size_t)tk * 256 + (c - DI)] = r;
  } else if (c < CONVD + NH) {
    const int hh = c - CONVD;
    float x = bf2f(projbf[(size_t)tk * DPADR + DI + c]) + dt_bias[hh];
    float dt = (x > 20.f) ? x : log1pf(__expf(x));
    dtg[(size_t)tk * NH + hh] = dt;
  }
}

// ---------------- SSD kernel 1 ----------------
__global__ __launch_bounds__(256)
void k_ssd1(const unsigned short* __restrict__ xbf, const unsigned short* __restrict__ bcbf,
            const float* __restrict__ dtg, const float* __restrict__ A_log,
            const float* __restrict__ Dv, unsigned short* __restrict__ ybuf,
            unsigned short* __restrict__ Sc, float* __restrict__ dtsum) {
  __shared__ __align__(16) char smem[60928];
  unsigned short* sBs  = (unsigned short*)(smem);
  unsigned short* sCs  = (unsigned short*)(smem + 16384);
  unsigned short* sMs  = (unsigned short*)(smem + 16384);
  unsigned short* sBsT = (unsigned short*)(smem + 32768);
  unsigned short* sXsT = (unsigned short*)(smem + 51200);
  float* sdt = (float*)(smem + 60416);
  float* sdl = (float*)(smem + 60672);

  const int bi = blockIdx.x;
  const int ch = bi & 31, h = (bi >> 5) & 63, b = bi >> 11;
  const int bh = b * NH + h;
  const int tok0 = b * LSEQ + ch * QC;
  const int t = threadIdx.x;
  const int w = t >> 6, l = t & 63, lr = l & 15, hi = l >> 4;
  const float Ah = -__expf(A_log[h]);
  const float Dh = Dv[h];

  {
    const int srow = t >> 4, scol = (t & 15) * 8;
#pragma unroll
    for (int i = 0; i < 4; i++) {
      const unsigned short* gb = bcbf + (size_t)(tok0 + srow + 16 * i) * 256 + scol;
      GLL(gb, (char*)sBs + i * 4096 + w * 1024);
      GLL(gb + 128, (char*)sCs + i * 4096 + w * 1024);
    }
  }
  if (t < QC) sdt[t] = dtg[(size_t)(tok0 + t) * NH + h];
  __syncthreads();
  if (t < QC) sdl[t] = sdt[t];
  __syncthreads();
  for (int off = 1; off < QC; off <<= 1) {
    float v = 0.f;
    if (t < QC && t >= off) v = sdl[t - off];
    __syncthreads();
    if (t < QC) sdl[t] += v;
    __syncthreads();
  }

  {
    const int s = t >> 2;
    const float DlQ = sdl[QC - 1];
    const float csc = __expf(Ah * (DlQ - sdl[s])) * sdt[s];
    const int n0 = (t & 3) * 32;
#pragma unroll
    for (int j = 0; j < 32; j++) {
      float bv = bf2f(sBs[s * 128 + n0 + j]);
      sBsT[(n0 + j) * 72 + s] = f2bf(csc * bv);
    }
    const int p0 = (t & 3) * 16;
    const unsigned short* gx = xbf + (size_t)(tok0 + s) * DI + h * 64 + p0;
    union { uint4 v; unsigned short u[8]; } x0, x1;
    x0.v = *(const uint4*)gx;
    x1.v = *(const uint4*)(gx + 8);
#pragma unroll
    for (int j = 0; j < 8; j++) {
      sXsT[(p0 + j) * 72 + s] = x0.u[j];
      sXsT[(p0 + 8 + j) * 72 + s] = x1.u[j];
    }
  }
  __syncthreads();

  f32x4 accS[4];
#pragma unroll
  for (int jf = 0; jf < 4; jf++) accS[jf] = (f32x4){0.f, 0.f, 0.f, 0.f};
#pragma unroll
  for (int ks = 0; ks < 4; ks++) {
    bf16x8 a = *(const bf16x8*)&sBs[(w * 16 + lr) * 128 + ks * 32 + hi * 8];
#pragma unroll
    for (int jf = 0; jf < 4; jf++) {
      bf16x8 bbq = *(const bf16x8*)&sCs[(jf * 16 + lr) * 128 + ks * 32 + hi * 8];
      accS[jf] = __builtin_amdgcn_mfma_f32_16x16x32_bf16(a, bbq, accS[jf], 0, 0, 0);
    }
  }
  __syncthreads();

  {
    const int s0 = w * 16 + hi * 4;
#pragma unroll
    for (int jf = 0; jf < 4; jf++) {
      const int tt = jf * 16 + lr;
      const float dlt = sdl[tt];
      unsigned short mv[4];
#pragma unroll
      for (int r = 0; r < 4; r++) {
        const int ss = s0 + r;
        float val = 0.f;
        if (ss <= tt) val = accS[jf][r] * __expf(Ah * (dlt - sdl[ss])) * sdt[ss];
        mv[r] = f2bf(val);
      }
      *(ushort4*)&sMs[tt * 72 + s0] = *(ushort4*)mv;
    }
  }
  __syncthreads();

  {
    f32x4 accY[4];
#pragma unroll
    for (int jf = 0; jf < 4; jf++) accY[jf] = (f32x4){0.f, 0.f, 0.f, 0.f};
#pragma unroll
    for (int ks = 0; ks < 2; ks++) {
      bf16x8 a = *(const bf16x8*)&sMs[(w * 16 + lr) * 72 + ks * 32 + hi * 8];
#pragma unroll
      for (int jf = 0; jf < 4; jf++) {
        bf16x8 bbq = *(const bf16x8*)&sXsT[(jf * 16 + lr) * 72 + ks * 32 + hi * 8];
        accY[jf] = __builtin_amdgcn_mfma_f32_16x16x32_bf16(a, bbq, accY[jf], 0, 0, 0);
      }
    }
#pragma unroll
    for (int jf = 0; jf < 4; jf++)
#pragma unroll
      for (int r = 0; r < 4; r++) {
        const int tt = w * 16 + hi * 4 + r;
        const int pp = jf * 16 + lr;
        float xv = bf2f(sXsT[pp * 72 + tt]);
        ybuf[(size_t)(tok0 + tt) * DI + h * 64 + pp] = f2bf(accY[jf][r] + Dh * xv);
      }
  }

  {
    f32x4 accT[8];
#pragma unroll
    for (int jf = 0; jf < 8; jf++) accT[jf] = (f32x4){0.f, 0.f, 0.f, 0.f};
#pragma unroll
    for (int ks = 0; ks < 2; ks++) {
      bf16x8 a = *(const bf16x8*)&sXsT[(w * 16 + lr) * 72 + ks * 32 + hi * 8];
#pragma unroll
      for (int jf = 0; jf < 8; jf++) {
        bf16x8 bbq = *(const bf16x8*)&sBsT[(jf * 16 + lr) * 72 + ks * 32 + hi * 8];
        accT[jf] = __builtin_amdgcn_mfma_f32_16x16x32_bf16(a, bbq, accT[jf], 0, 0, 0);
      }
    }
    unsigned short* sc = Sc + ((size_t)bh * NCH + ch) * (PDIM * NSTATE);
#pragma unroll
    for (int jf = 0; jf < 8; jf++)
#pragma unroll
      for (int r = 0; r < 4; r++) {
        const int pp = w * 16 + hi * 4 + r;
        const int nn = jf * 16 + lr;
        sc[pp * NSTATE + nn] = f2bf(accT[jf][r]);
      }
  }
  if (t == 0) dtsum[bh * NCH + ch] = sdl[QC - 1];
}

// ---------------- SSD kernel 2 ----------------
__global__ __launch_bounds__(256)
void k_ssd2(const float* __restrict__ A_log, const float* __restrict__ dtsum,
            unsigned short* __restrict__ ScHt) {
  const int blk = blockIdx.x;
  const int bh = blk >> 3, pg = blk & 7;
  const int t = threadIdx.x;
  const int p = pg * 8 + (t >> 5), n0 = (t & 31) * 4;
  const int h = bh & 63;
  const float Ah = -__expf(A_log[h]);
  float H[4] = {0.f, 0.f, 0.f, 0.f};
  for (int c = 0; c < NCH; c++) {
    size_t base = (((size_t)bh * NCH + c) * PDIM + p) * NSTATE + n0;
    ushort4 sv = *(const ushort4*)&ScHt[base];
    float dec = __expf(Ah * dtsum[bh * NCH + c]);
    ushort4 hv;
    hv.x = f2bf(H[0]); hv.y = f2bf(H[1]); hv.z = f2bf(H[2]); hv.w = f2bf(H[3]);
    *(ushort4*)&ScHt[base] = hv;
    H[0] = dec * H[0] + bf2f(sv.x);
    H[1] = dec * H[1] + bf2f(sv.y);
    H[2] = dec * H[2] + bf2f(sv.z);
    H[3] = dec * H[3] + bf2f(sv.w);
  }
}

// ---------------- SSD kernel 3 ----------------
__global__ __launch_bounds__(256)
void k_ssd3(const unsigned short* __restrict__ bcbf, const unsigned short* __restrict__ Ht,
            const float* __restrict__ dtg, const float* __restrict__ A_log,
            unsigned short* __restrict__ ybuf) {
  __shared__ __align__(16) char smem[33280];
  unsigned short* sCs = (unsigned short*)(smem);
  unsigned short* sHt = (unsigned short*)(smem + 16384);
  float* sdt = (float*)(smem + 32768);
  float* sdl = (float*)(smem + 33024);

  const int bi = blockIdx.x;
  const int ch = bi & 31, h = (bi >> 5) & 63, b = bi >> 11;
  const int bh = b * NH + h;
  const int tok0 = b * LSEQ + ch * QC;
  const int t = threadIdx.x;
  const int w = t >> 6, l = t & 63, lr = l & 15, hi = l >> 4;
  const float Ah = -__expf(A_log[h]);

  {
    const int srow = t >> 4, scol = (t & 15) * 8;
    const unsigned short* gh = Ht + ((size_t)bh * NCH + ch) * (PDIM * NSTATE);
#pragma unroll
    for (int i = 0; i < 4; i++) {
      const unsigned short* gc = bcbf + (size_t)(tok0 + srow + 16 * i) * 256 + 128 + scol;
      GLL(gc, (char*)sCs + i * 4096 + w * 1024);
      GLL(gh + i * 2048 + t * 8, (char*)sHt + i * 4096 + w * 1024);
    }
  }
  if (t < QC) sdt[t] = dtg[(size_t)(tok0 + t) * NH + h];
  __syncthreads();
  if (t < QC) sdl[t] = sdt[t];
  __syncthreads();
  for (int off = 1; off < QC; off <<= 1) {
    float v = 0.f;
    if (t < QC && t >= off) v = sdl[t - off];
    __syncthreads();
    if (t < QC) sdl[t] += v;
    __syncthreads();
  }

  f32x4 acc[4];
#pragma unroll
  for (int jf = 0; jf < 4; jf++) acc[jf] = (f32x4){0.f, 0.f, 0.f, 0.f};
#pragma unroll
  for (int ks = 0; ks < 4; ks++) {
    bf16x8 a = *(const bf16x8*)&sCs[(w * 16 + lr) * 128 + ks * 32 + hi * 8];
#pragma unroll
    for (int jf = 0; jf < 4; jf++) {
      bf16x8 bbq = *(const bf16x8*)&sHt[(jf * 16 + lr) * 128 + ks * 32 + hi * 8];
      acc[jf] = __builtin_amdgcn_mfma_f32_16x16x32_bf16(a, bbq, acc[jf], 0, 0, 0);
    }
  }
#pragma unroll
  for (int jf = 0; jf < 4; jf++)
#pragma unroll
    for (int r = 0; r < 4; r++) {
      const int tt = w * 16 + hi * 4 + r;
      const int pp = jf * 16 + lr;
      const float dec = __expf(Ah * sdl[tt]);
      const size_t o = (size_t)(tok0 + tt) * DI + h * 64 + pp;
      ybuf[o] = f2bf(bf2f(ybuf[o]) + dec * acc[jf][r]);
    }
}

// ---------------- workspace layout (bytes) ----------------
static const size_t OFF_WBF_IN  = 0;
static const size_t OFF_WBF_OUT = 35651584;
static const size_t OFF_WBF_GU  = 52428800;
static const size_t OFF_WBF_DN  = 119537664;
static const size_t OFF_RESID   = 153092096;
static const size_t OFF_HSBF    = 186646528;
static const size_t OFF_PROJ    = 203423744;
static const size_t OFF_XBF     = 274726912;
static const size_t OFF_BCBF    = 308281344;
static const size_t OFF_DTG     = 310378496;
static const size_t OFF_YBUF    = 311427072;
static const size_t OFF_SC      = 344981504;
static const size_t OFF_DTSUM   = 412090368;

extern "C" void kernel_launch(void* const* d_in, const int* in_sizes, int n_in,
                              void* d_out, int out_size, void* d_ws, size_t ws_size,
                              hipStream_t stream) {
  (void)in_sizes; (void)n_in; (void)out_size; (void)ws_size;
  const float* hidden   = (const float*)d_in[1];
  const float* resin    = (const float*)d_in[2];
  const float* w_inproj = (const float*)d_in[3];
  const float* conv_w   = (const float*)d_in[4];
  const float* conv_b   = (const float*)d_in[5];
  const float* A_log    = (const float*)d_in[6];
  const float* Dvec     = (const float*)d_in[7];
  const float* dt_bias  = (const float*)d_in[8];
  const float* w_mix    = (const float*)d_in[9];
  const float* w_outp   = (const float*)d_in[10];
  const float* w_ln1    = (const float*)d_in[11];
  const float* w_ln2    = (const float*)d_in[12];
  const float* w_gu     = (const float*)d_in[13];
  const float* w_dn     = (const float*)d_in[14];

  char* ws = (char*)d_ws;
  unsigned short* wbf_in  = (unsigned short*)(ws + OFF_WBF_IN);
  unsigned short* wbf_out = (unsigned short*)(ws + OFF_WBF_OUT);
  unsigned short* wbf_gu  = (unsigned short*)(ws + OFF_WBF_GU);
  unsigned short* wbf_dn  = (unsigned short*)(ws + OFF_WBF_DN);
  float*          residb  = (float*)(ws + OFF_RESID);
  unsigned short* hsbf    = (unsigned short*)(ws + OFF_HSBF);
  unsigned short* projbf  = (unsigned short*)(ws + OFF_PROJ);
  unsigned short* actbf   = (unsigned short*)(ws + OFF_PROJ);   // alias
  unsigned short* xbf     = (unsigned short*)(ws + OFF_XBF);
  unsigned short* ynormbf = (unsigned short*)(ws + OFF_XBF);    // alias
  unsigned short* bcbf    = (unsigned short*)(ws + OFF_BCBF);
  float*          dtgb    = (float*)(ws + OFF_DTG);
  unsigned short* ybuf    = (unsigned short*)(ws + OFF_YBUF);
  unsigned short* scht    = (unsigned short*)(ws + OFF_SC);
  float*          dtsumb  = (float*)(ws + OFF_DTSUM);

  float* out0 = (float*)d_out;
  float* res2 = out0 + (size_t)T_TOK * HID;

  // 0) all weight conversions in one kernel
  k_cvt_all<<<37376, 256, 0, stream>>>(w_inproj, w_outp, w_gu, w_dn,
                                       wbf_in, wbf_out, wbf_gu, wbf_dn);
  // 1) residual add + input rmsnorm
  k_addnorm<<<T_TOK, 256, 0, stream>>>(hidden, resin, w_ln1, residb, hsbf);
  // 2) in_proj GEMM (8-phase) -> proj bf16 [4096][8704]
  gemm8p<0><<<34 * 16, 512, 0, stream>>>(hsbf, wbf_in, HID, DPADR, projbf);
  // 3) causal conv + silu + fused dt softplus
  k_conv<<<dim3(18, T_TOK), 256, 0, stream>>>(projbf, conv_w, conv_b, dt_bias, xbf, bcbf, dtgb);
  // 4) SSD intra + chunk states
  k_ssd1<<<4096, 256, 0, stream>>>(xbf, bcbf, dtgb, A_log, Dvec, ybuf, scht, dtsumb);
  // 5) SSD serial combine
  k_ssd2<<<1024, 256, 0, stream>>>(A_log, dtsumb, scht);
  // 6) SSD inter-chunk
  k_ssd3<<<4096, 256, 0, stream>>>(bcbf, scht, dtgb, A_log, ybuf);
  // 7) gate + mixer rmsnorm -> ynorm bf16
  k_gatenorm<<<T_TOK, 256, 0, stream>>>(ybuf, projbf, w_mix, ynormbf);
  // 8) out_proj GEMM + residual -> residual2 (output 1)
  gemm8<1, 128><<<8 * 32, 512, 0, stream>>>(ynormbf, wbf_out, DI, HID, res2, residb);
  // 9) pre-FF rmsnorm -> hs2 bf16
  k_rmsnorm_bf<<<T_TOK, 256, 0, stream>>>(res2, w_ln2, hsbf);
  // 10) gate_up GEMM (8-phase, fused silu-pair epilogue) -> act bf16
  gemm8p<2><<<64 * 16, 512, 0, stream>>>(hsbf, wbf_gu, HID, IM, actbf);
  // 11) down GEMM -> out (output 0)
  gemm8<3, 128><<<8 * 32, 512, 0, stream>>>(actbf, wbf_dn, IM, HID, out0, nullptr);
}

// Round 11
// 994.759 us; speedup vs baseline: 1.1288x; 1.0328x over previous
//
#include <hip/hip_runtime.h>

// ---------------- problem constants ----------------
#define T_TOK 4096          // BB*L tokens
#define HID   2048
#define DI    4096
#define NH    64
#define PDIM  64
#define NSTATE 128
#define IM    8192
#define LSEQ  2048
#define CONVD 4352          // DI + 2*G*N
#define DPROJ 8512          // 2*DI + 2*G*N + NH
#define DPADR 8704          // padded to 34*256
#define QC    64            // SSD chunk length
#define NCH   32            // chunks per sequence

typedef __bf16 bf16x8 __attribute__((ext_vector_type(8)));
typedef float  f32x4  __attribute__((ext_vector_type(4)));

__device__ __forceinline__ unsigned short f2bf(float f) {
  unsigned u = __float_as_uint(f);
  u = (u + 0x7fffu + ((u >> 16) & 1u)) >> 16;
  return (unsigned short)u;
}
__device__ __forceinline__ float bf2f(unsigned short h) {
  return __uint_as_float(((unsigned)h) << 16);
}
__device__ __forceinline__ float siluf(float x) {
  return x / (1.f + __expf(-x));
}

#define GLL(gaddr, laddr) __builtin_amdgcn_global_load_lds( \
    (const __attribute__((address_space(1))) void*)(gaddr), \
    (__attribute__((address_space(3))) void*)(laddr), 16, 0, 0)

// ---------------- merged weight conversion (all 4 weights, 8 elems/thread) ----------------
__device__ __forceinline__ void cvt8(const float* __restrict__ s, unsigned short* __restrict__ d) {
  float4 v0 = *(const float4*)s;
  float4 v1 = *(const float4*)(s + 4);
  unsigned short o[8];
  o[0] = f2bf(v0.x); o[1] = f2bf(v0.y); o[2] = f2bf(v0.z); o[3] = f2bf(v0.w);
  o[4] = f2bf(v1.x); o[5] = f2bf(v1.y); o[6] = f2bf(v1.z); o[7] = f2bf(v1.w);
  *(uint4*)d = *(const uint4*)o;
}

// region thresholds in 8-elem units
#define CV_IN_END  2228224ULL   // DPADR*HID/8
#define CV_OUT_END 3276800ULL   // + 2048*4096/8
#define CV_GU_END  7471104ULL   // + 2*IM*2048/8
#define CV_DN_END  9568256ULL   // + 2048*8192/8

__global__ __launch_bounds__(256)
void k_cvt_all(const float* __restrict__ w_in, const float* __restrict__ w_out,
               const float* __restrict__ w_gu, const float* __restrict__ w_dn,
               unsigned short* __restrict__ d_in, unsigned short* __restrict__ d_out,
               unsigned short* __restrict__ d_gu, unsigned short* __restrict__ d_dn) {
  size_t gid = (size_t)blockIdx.x * 256 + threadIdx.x;
  if (gid < CV_IN_END) {
    size_t idx8 = gid * 8;
    int r = (int)(idx8 >> 11), k = (int)(idx8 & 2047);
    if (r < DPROJ) {
      cvt8(&w_in[(size_t)r * HID + k], d_in + idx8);
    } else {
      uint4 z = {0, 0, 0, 0};
      *(uint4*)(d_in + idx8) = z;
    }
  } else if (gid < CV_OUT_END) {
    size_t idx8 = (gid - CV_IN_END) * 8;
    cvt8(w_out + idx8, d_out + idx8);
  } else if (gid < CV_GU_END) {
    size_t idx8 = (gid - CV_OUT_END) * 8;
    int r = (int)(idx8 >> 11), k = (int)(idx8 & 2047);
    int g = r >> 6, j = r & 63;
    int srcr = (j < 32) ? (g * 32 + j) : (IM + g * 32 + (j - 32));
    cvt8(&w_gu[(size_t)srcr * HID + k], d_gu + idx8);
  } else if (gid < CV_DN_END) {
    size_t idx8 = (gid - CV_GU_END) * 8;
    cvt8(w_dn + idx8, d_dn + idx8);
  }
}

// ---------------- pipelined BMx256 GEMM (R5/R8 known-good structure) ----------------
// C[M,N] = A[M,K] * W[N,K]^T, M fixed 4096. 512 thr = 8 waves (2M x 4N).
// BM=256: per-wave 128x64, MREP=8. BM=128: per-wave 64x64, MREP=4.
// One barrier + one vmcnt(0) per K-tile (waited loads issued a full tile earlier);
// ds_reads distributed across MFMA clusters; no intra-tile barriers -> waves drift.
// NOTE: no s_setprio — m190 measured it NEGATIVE on barrier-lockstep 1-phase GEMMs;
// three structured-schedule ports (R6/R7/R10) all lost to this loop — closed.
// EPI: 0 = bf16 store, 1 = f32 + resid, 2 = gate-pair silu bf16, 3 = f32 store
template <int EPI, int BM>
__global__ __launch_bounds__(512, 2)
void gemm8(const unsigned short* __restrict__ A, const unsigned short* __restrict__ W,
           int K, int ldo, void* __restrict__ outp,
           const float* __restrict__ resid) {
  constexpr int MREP  = BM / 32;          // A frags per wave per kk
  constexpr int ABYT  = BM * 128;         // A region bytes per buffer
  constexpr int BUFB  = ABYT + 32768;     // buffer stride
  constexpr int NTM   = 4096 / BM;
  __shared__ __align__(16) char smem[2 * BUFB];
  const int t = threadIdx.x;
  const int w = t >> 6, l = t & 63;
  const int lr = l & 15, hi = l >> 4;
  const int wr = w >> 2, wc = w & 3;

  // T1: bijective XCD swizzle over tn-major enumeration (grid % 8 == 0)
  const int q = (int)gridDim.x >> 3;
  const int bid = blockIdx.x;
  const int id2 = (bid & 7) * q + (bid >> 3);
  const int tn = id2 / NTM, tm = id2 % NTM;
  const int m0b = tm * BM, n0b = tn << 8;

  // staging lane constants; source col pre-swizzled (byte bits 5,6 <- row bits 2,3)
  const int srow = t >> 3;
  const int scole = ((t & 7) << 3) ^ ((t & 32) ? 16 : 0) ^ ((t & 64) ? 32 : 0);
  const unsigned short* Ag = A + (size_t)(m0b + srow) * K + scole;
  const unsigned short* Wg = W + (size_t)(n0b + srow) * K + scole;
  const int ldsw = w * 1024;

  // ds_read swizzled byte bases per kk
  const int fa = ((lr & 4) ? 32 : 0) | ((lr & 8) ? 64 : 0);
  const int arow = (wr * (BM / 2) + lr) * 128 + hi * 16;
  const int brow = (wc * 64 + lr) * 128 + hi * 16;
  const int aoff0 = arow ^ fa, aoff1 = (arow + 64) ^ fa;
  const int boff0 = brow ^ fa, boff1 = (brow + 64) ^ fa;

#define ISSUE_A(jt, bb) do {                                                    \
    _Pragma("unroll")                                                           \
    for (int p_ = 0; p_ < BM / 64; ++p_)                                        \
      GLL(Ag + (size_t)(p_ * 64) * K + (size_t)(jt) * 64,                       \
          smem + (bb) * BUFB + p_ * 8192 + ldsw); } while (0)
#define ISSUE_B(jt, bb) do {                                                    \
    _Pragma("unroll")                                                           \
    for (int p_ = 0; p_ < 4; ++p_)                                              \
      GLL(Wg + (size_t)(p_ * 64) * K + (size_t)(jt) * 64,                       \
          smem + (bb) * BUFB + ABYT + p_ * 8192 + ldsw); } while (0)

#define RDF(off, base) (*(const bf16x8*)((base) + (off)))
#define MF(P, x, y, c0, c1, c2, c3) do {                                                     \
    acc[2*(P)  ][0] = __builtin_amdgcn_mfma_f32_16x16x32_bf16((x),(c0),acc[2*(P)  ][0],0,0,0);\
    acc[2*(P)+1][0] = __builtin_amdgcn_mfma_f32_16x16x32_bf16((y),(c0),acc[2*(P)+1][0],0,0,0);\
    acc[2*(P)  ][1] = __builtin_amdgcn_mfma_f32_16x16x32_bf16((x),(c1),acc[2*(P)  ][1],0,0,0);\
    acc[2*(P)+1][1] = __builtin_amdgcn_mfma_f32_16x16x32_bf16((y),(c1),acc[2*(P)+1][1],0,0,0);\
    acc[2*(P)  ][2] = __builtin_amdgcn_mfma_f32_16x16x32_bf16((x),(c2),acc[2*(P)  ][2],0,0,0);\
    acc[2*(P)+1][2] = __builtin_amdgcn_mfma_f32_16x16x32_bf16((y),(c2),acc[2*(P)+1][2],0,0,0);\
    acc[2*(P)  ][3] = __builtin_amdgcn_mfma_f32_16x16x32_bf16((x),(c3),acc[2*(P)  ][3],0,0,0);\
    acc[2*(P)+1][3] = __builtin_amdgcn_mfma_f32_16x16x32_bf16((y),(c3),acc[2*(P)+1][3],0,0,0);\
    } while (0)

  f32x4 acc[MREP][4];
#pragma unroll
  for (int m = 0; m < MREP; m++)
#pragma unroll
    for (int n = 0; n < 4; n++) acc[m][n] = (f32x4){0.f, 0.f, 0.f, 0.f};

  const int nkt = K >> 6;
  // prologue: stage tile 0 into buf 0
  ISSUE_A(0, 0); ISSUE_B(0, 0);

  for (int j = 0; j < nkt; ++j) {
    const int cur = j & 1;
    const char* Ab = smem + cur * BUFB;
    const char* Bb = Ab + ABYT;
    asm volatile("s_waitcnt vmcnt(0)" ::: "memory");   // waits loads issued a full tile ago
    __builtin_amdgcn_s_barrier();                       // all waves' slices resident (WAR-safe)
    __builtin_amdgcn_sched_barrier(0);
    if (j + 1 < nkt) { ISSUE_A(j + 1, cur ^ 1); ISSUE_B(j + 1, cur ^ 1); }
    bf16x8 b0 = RDF(boff0, Bb), b1 = RDF(boff0 + 2048, Bb),
           b2 = RDF(boff0 + 4096, Bb), b3 = RDF(boff0 + 6144, Bb);
    bf16x8 af0 = RDF(aoff0, Ab), af1 = RDF(aoff0 + 2048, Ab);
    bf16x8 af2, af3, b4, b5, b6, b7;
    if constexpr (MREP == 8) {
      af2 = RDF(aoff0 + 4096, Ab); af3 = RDF(aoff0 + 6144, Ab);
      MF(0, af0, af1, b0, b1, b2, b3);
      af0 = RDF(aoff0 + 8192, Ab); af1 = RDF(aoff0 + 10240, Ab);
      MF(1, af2, af3, b0, b1, b2, b3);
      af2 = RDF(aoff0 + 12288, Ab); af3 = RDF(aoff0 + 14336, Ab);
      MF(2, af0, af1, b0, b1, b2, b3);
      b4 = RDF(boff1, Bb); b5 = RDF(boff1 + 2048, Bb);
      b6 = RDF(boff1 + 4096, Bb); b7 = RDF(boff1 + 6144, Bb);
      af0 = RDF(aoff1, Ab); af1 = RDF(aoff1 + 2048, Ab);
      MF(3, af2, af3, b0, b1, b2, b3);
      af2 = RDF(aoff1 + 4096, Ab); af3 = RDF(aoff1 + 6144, Ab);
      MF(0, af0, af1, b4, b5, b6, b7);
      af0 = RDF(aoff1 + 8192, Ab); af1 = RDF(aoff1 + 10240, Ab);
      MF(1, af2, af3, b4, b5, b6, b7);
      af2 = RDF(aoff1 + 12288, Ab); af3 = RDF(aoff1 + 14336, Ab);
      MF(2, af0, af1, b4, b5, b6, b7);
      MF(3, af2, af3, b4, b5, b6, b7);
    } else {
      af2 = RDF(aoff0 + 4096, Ab); af3 = RDF(aoff0 + 6144, Ab);
      MF(0, af0, af1, b0, b1, b2, b3);
      b4 = RDF(boff1, Bb); b5 = RDF(boff1 + 2048, Bb);
      b6 = RDF(boff1 + 4096, Bb); b7 = RDF(boff1 + 6144, Bb);
      af0 = RDF(aoff1, Ab); af1 = RDF(aoff1 + 2048, Ab);
      MF(1, af2, af3, b0, b1, b2, b3);
      af2 = RDF(aoff1 + 4096, Ab); af3 = RDF(aoff1 + 6144, Ab);
      MF(0, af0, af1, b4, b5, b6, b7);
      MF(1, af2, af3, b4, b5, b6, b7);
    }
  }

  if constexpr (EPI == 0) {
    unsigned short* op = (unsigned short*)outp;
#pragma unroll
    for (int m = 0; m < MREP; m++)
#pragma unroll
      for (int n = 0; n < 4; n++)
#pragma unroll
        for (int r = 0; r < 4; r++) {
          int row = m0b + wr * (BM / 2) + m * 16 + hi * 4 + r;
          int col = n0b + wc * 64 + n * 16 + lr;
          op[(size_t)row * ldo + col] = f2bf(acc[m][n][r]);
        }
  } else if constexpr (EPI == 2) {
    unsigned short* op = (unsigned short*)outp;
    const int gbase = (n0b + wc * 64) >> 1;
#pragma unroll
    for (int m = 0; m < MREP; m++)
#pragma unroll
      for (int n = 0; n < 2; n++)
#pragma unroll
        for (int r = 0; r < 4; r++) {
          int row = m0b + wr * (BM / 2) + m * 16 + hi * 4 + r;
          int col = gbase + n * 16 + lr;
          float g = acc[m][n][r], u = acc[m][n + 2][r];
          op[(size_t)row * ldo + col] = f2bf(siluf(g) * u);
        }
  } else {
    float* op = (float*)outp;
#pragma unroll
    for (int m = 0; m < MREP; m++)
#pragma unroll
      for (int n = 0; n < 4; n++)
#pragma unroll
        for (int r = 0; r < 4; r++) {
          int row = m0b + wr * (BM / 2) + m * 16 + hi * 4 + r;
          int col = n0b + wc * 64 + n * 16 + lr;
          float v = acc[m][n][r];
          if constexpr (EPI == 1) v += resid[(size_t)row * ldo + col];
          op[(size_t)row * ldo + col] = v;
        }
  }
#undef ISSUE_A
#undef ISSUE_B
#undef RDF
#undef MF
}

// ---------------- norms ----------------
__device__ __forceinline__ float block_reduce_sum256(float v, float* sred) {
#pragma unroll
  for (int m = 32; m; m >>= 1) v += __shfl_xor(v, m);
  int t = threadIdx.x;
  if ((t & 63) == 0) sred[t >> 6] = v;
  __syncthreads();
  return sred[0] + sred[1] + sred[2] + sred[3];
}

__global__ __launch_bounds__(256)
void k_addnorm(const float* __restrict__ hin, const float* __restrict__ rin,
               const float* __restrict__ wln, float* __restrict__ rout,
               unsigned short* __restrict__ hbf) {
  __shared__ float sred[4];
  const int tok = blockIdx.x, t = threadIdx.x;
  const size_t base = (size_t)tok * HID + t * 8;
  float4 a0 = *(const float4*)&hin[base];
  float4 a1 = *(const float4*)&hin[base + 4];
  float4 b0 = *(const float4*)&rin[base];
  float4 b1 = *(const float4*)&rin[base + 4];
  float v[8] = {a0.x + b0.x, a0.y + b0.y, a0.z + b0.z, a0.w + b0.w,
                a1.x + b1.x, a1.y + b1.y, a1.z + b1.z, a1.w + b1.w};
  float ss = 0.f;
#pragma unroll
  for (int j = 0; j < 8; j++) ss += v[j] * v[j];
  float tot = block_reduce_sum256(ss, sred);
  float rms = rsqrtf(tot * (1.f / HID) + 1e-5f);
  *(float4*)&rout[base] = (float4){v[0], v[1], v[2], v[3]};
  *(float4*)&rout[base + 4] = (float4){v[4], v[5], v[6], v[7]};
  float4 w0 = *(const float4*)&wln[t * 8];
  float4 w1 = *(const float4*)&wln[t * 8 + 4];
  float wa[8] = {w0.x, w0.y, w0.z, w0.w, w1.x, w1.y, w1.z, w1.w};
  unsigned short o[8];
#pragma unroll
  for (int j = 0; j < 8; j++) o[j] = f2bf(v[j] * rms * wa[j]);
  *(ushort4*)&hbf[base] = *(ushort4*)&o[0];
  *(ushort4*)&hbf[base + 4] = *(ushort4*)&o[4];
}

__global__ __launch_bounds__(256)
void k_rmsnorm_bf(const float* __restrict__ src, const float* __restrict__ wln,
                  unsigned short* __restrict__ dst) {
  __shared__ float sred[4];
  const int tok = blockIdx.x, t = threadIdx.x;
  const size_t base = (size_t)tok * HID + t * 8;
  float4 a0 = *(const float4*)&src[base];
  float4 a1 = *(const float4*)&src[base + 4];
  float v[8] = {a0.x, a0.y, a0.z, a0.w, a1.x, a1.y, a1.z, a1.w};
  float ss = 0.f;
#pragma unroll
  for (int j = 0; j < 8; j++) ss += v[j] * v[j];
  float tot = block_reduce_sum256(ss, sred);
  float rms = rsqrtf(tot * (1.f / HID) + 1e-5f);
  float4 w0 = *(const float4*)&wln[t * 8];
  float4 w1 = *(const float4*)&wln[t * 8 + 4];
  float wa[8] = {w0.x, w0.y, w0.z, w0.w, w1.x, w1.y, w1.z, w1.w};
  unsigned short o[8];
#pragma unroll
  for (int j = 0; j < 8; j++) o[j] = f2bf(v[j] * rms * wa[j]);
  *(ushort4*)&dst[base] = *(ushort4*)&o[0];
  *(ushort4*)&dst[base + 4] = *(ushort4*)&o[4];
}

__global__ __launch_bounds__(256)
void k_gatenorm(const unsigned short* __restrict__ ybuf, const unsigned short* __restrict__ projbf,
                const float* __restrict__ wmix, unsigned short* __restrict__ ynorm) {
  __shared__ float sred[4];
  const int tok = blockIdx.x, t = threadIdx.x;
  const size_t yb = (size_t)tok * DI;
  const size_t pb = (size_t)tok * DPADR;
  float g[16];
  float ss = 0.f;
#pragma unroll
  for (int j = 0; j < 16; j++) {
    int idx = j * 256 + t;
    float yv = bf2f(ybuf[yb + idx]);
    float z = bf2f(projbf[pb + idx]);
    float gg = yv * siluf(z);
    g[j] = gg;
    ss += gg * gg;
  }
  float tot = block_reduce_sum256(ss, sred);
  float rms = rsqrtf(tot * (1.f / DI) + 1e-5f);
#pragma unroll
  for (int j = 0; j < 16; j++) {
    int idx = j * 256 + t;
    ynorm[yb + idx] = f2bf(g[j] * rms * wmix[idx]);
  }
}

// ---------------- conv (depthwise causal K=4) + silu + fused dt softplus ----------------
__global__ __launch_bounds__(256)
void k_conv(const unsigned short* __restrict__ projbf, const float* __restrict__ cw,
            const float* __restrict__ cb, const float* __restrict__ dt_bias,
            unsigned short* __restrict__ xbf, unsigned short* __restrict__ bcbf,
            float* __restrict__ dtg) {
  const int c = blockIdx.x * 256 + threadIdx.x;   // 0..4607
  const int tk = blockIdx.y;                      // token
  if (c < CONVD) {
    const int lpos = tk & (LSEQ - 1);
    float4 wv = *(const float4*)&cw[c * 4];
    float wk[4] = {wv.x, wv.y, wv.z, wv.w};
    float acc = cb[c];
#pragma unroll
    for (int k = 0; k < 4; k++) {
      int lp = lpos - 3 + k;
      if (lp >= 0) acc += bf2f(projbf[(size_t)(tk - 3 + k) * DPADR + DI + c]) * wk[k];
    }
    unsigned short r = f2bf(siluf(acc));
    if (c < DI) xbf[(size_t)tk * DI + c] = r;
    else        bcbf[(size_t)tk * 256 + (c - DI)] = r;
  } else if (c < CONVD + NH) {
    const int hh = c - CONVD;
    float x = bf2f(projbf[(size_t)tk * DPADR + DI + c]) + dt_bias[hh];
    float dt = (x > 20.f) ? x : log1pf(__expf(x));
    dtg[(size_t)tk * NH + hh] = dt;
  }
}

// ---------------- SSD kernel 1: per (b,h,chunk) intra + chunk-state ----------------
__global__ __launch_bounds__(256)
void k_ssd1(const unsigned short* __restrict__ xbf, const unsigned short* __restrict__ bcbf,
            const float* __restrict__ dtg, const float* __restrict__ A_log,
            const float* __restrict__ Dv, unsigned short* __restrict__ ybuf,
            unsigned short* __restrict__ Sc, float* __restrict__ dtsum) {
  __shared__ __align__(16) char smem[60928];
  unsigned short* sBs  = (unsigned short*)(smem);          // [64][128]
  unsigned short* sCs  = (unsigned short*)(smem + 16384);  // [64][128]
  unsigned short* sMs  = (unsigned short*)(smem + 16384);  // alias: [64][72]
  unsigned short* sBsT = (unsigned short*)(smem + 32768);  // [128][72] scaled B^T
  unsigned short* sXsT = (unsigned short*)(smem + 51200);  // [64][72]  x^T
  float* sdt = (float*)(smem + 60416);
  float* sdl = (float*)(smem + 60672);

  const int bi = blockIdx.x;
  const int ch = bi & 31, h = (bi >> 5) & 63, b = bi >> 11;
  const int bh = b * NH + h;
  const int tok0 = b * LSEQ + ch * QC;
  const int t = threadIdx.x;
  const int w = t >> 6, l = t & 63, lr = l & 15, hi = l >> 4;
  const float Ah = -__expf(A_log[h]);
  const float Dh = Dv[h];

  {
    const int srow = t >> 4, scol = (t & 15) * 8;
#pragma unroll
    for (int i = 0; i < 4; i++) {
      const unsigned short* gb = bcbf + (size_t)(tok0 + srow + 16 * i) * 256 + scol;
      GLL(gb, (char*)sBs + i * 4096 + w * 1024);
      GLL(gb + 128, (char*)sCs + i * 4096 + w * 1024);
    }
  }
  if (t < QC) sdt[t] = dtg[(size_t)(tok0 + t) * NH + h];
  __syncthreads();
  if (t < QC) sdl[t] = sdt[t];
  __syncthreads();
  for (int off = 1; off < QC; off <<= 1) {
    float v = 0.f;
    if (t < QC && t >= off) v = sdl[t - off];
    __syncthreads();
    if (t < QC) sdl[t] += v;
    __syncthreads();
  }

  {
    const int s = t >> 2;
    const float DlQ = sdl[QC - 1];
    const float csc = __expf(Ah * (DlQ - sdl[s])) * sdt[s];
    const int n0 = (t & 3) * 32;
#pragma unroll
    for (int j = 0; j < 32; j++) {
      float bv = bf2f(sBs[s * 128 + n0 + j]);
      sBsT[(n0 + j) * 72 + s] = f2bf(csc * bv);
    }
    const int p0 = (t & 3) * 16;
    const unsigned short* gx = xbf + (size_t)(tok0 + s) * DI + h * 64 + p0;
    union { uint4 v; unsigned short u[8]; } x0, x1;
    x0.v = *(const uint4*)gx;
    x1.v = *(const uint4*)(gx + 8);
#pragma unroll
    for (int j = 0; j < 8; j++) {
      sXsT[(p0 + j) * 72 + s] = x0.u[j];
      sXsT[(p0 + 8 + j) * 72 + s] = x1.u[j];
    }
  }
  __syncthreads();

  f32x4 accS[4];
#pragma unroll
  for (int jf = 0; jf < 4; jf++) accS[jf] = (f32x4){0.f, 0.f, 0.f, 0.f};
#pragma unroll
  for (int ks = 0; ks < 4; ks++) {
    bf16x8 a = *(const bf16x8*)&sBs[(w * 16 + lr) * 128 + ks * 32 + hi * 8];
#pragma unroll
    for (int jf = 0; jf < 4; jf++) {
      bf16x8 bbq = *(const bf16x8*)&sCs[(jf * 16 + lr) * 128 + ks * 32 + hi * 8];
      accS[jf] = __builtin_amdgcn_mfma_f32_16x16x32_bf16(a, bbq, accS[jf], 0, 0, 0);
    }
  }
  __syncthreads();

  {
    const int s0 = w * 16 + hi * 4;
#pragma unroll
    for (int jf = 0; jf < 4; jf++) {
      const int tt = jf * 16 + lr;
      const float dlt = sdl[tt];
      unsigned short mv[4];
#pragma unroll
      for (int r = 0; r < 4; r++) {
        const int ss = s0 + r;
        float val = 0.f;
        if (ss <= tt) val = accS[jf][r] * __expf(Ah * (dlt - sdl[ss])) * sdt[ss];
        mv[r] = f2bf(val);
      }
      *(ushort4*)&sMs[tt * 72 + s0] = *(ushort4*)mv;
    }
  }
  __syncthreads();

  {
    f32x4 accY[4];
#pragma unroll
    for (int jf = 0; jf < 4; jf++) accY[jf] = (f32x4){0.f, 0.f, 0.f, 0.f};
#pragma unroll
    for (int ks = 0; ks < 2; ks++) {
      bf16x8 a = *(const bf16x8*)&sMs[(w * 16 + lr) * 72 + ks * 32 + hi * 8];
#pragma unroll
      for (int jf = 0; jf < 4; jf++) {
        bf16x8 bbq = *(const bf16x8*)&sXsT[(jf * 16 + lr) * 72 + ks * 32 + hi * 8];
        accY[jf] = __builtin_amdgcn_mfma_f32_16x16x32_bf16(a, bbq, accY[jf], 0, 0, 0);
      }
    }
#pragma unroll
    for (int jf = 0; jf < 4; jf++)
#pragma unroll
      for (int r = 0; r < 4; r++) {
        const int tt = w * 16 + hi * 4 + r;
        const int pp = jf * 16 + lr;
        float xv = bf2f(sXsT[pp * 72 + tt]);
        ybuf[(size_t)(tok0 + tt) * DI + h * 64 + pp] = f2bf(accY[jf][r] + Dh * xv);
      }
  }

  {
    f32x4 accT[8];
#pragma unroll
    for (int jf = 0; jf < 8; jf++) accT[jf] = (f32x4){0.f, 0.f, 0.f, 0.f};
#pragma unroll
    for (int ks = 0; ks < 2; ks++) {
      bf16x8 a = *(const bf16x8*)&sXsT[(w * 16 + lr) * 72 + ks * 32 + hi * 8];
#pragma unroll
      for (int jf = 0; jf < 8; jf++) {
        bf16x8 bbq = *(const bf16x8*)&sBsT[(jf * 16 + lr) * 72 + ks * 32 + hi * 8];
        accT[jf] = __builtin_amdgcn_mfma_f32_16x16x32_bf16(a, bbq, accT[jf], 0, 0, 0);
      }
    }
    unsigned short* sc = Sc + ((size_t)bh * NCH + ch) * (PDIM * NSTATE);
#pragma unroll
    for (int jf = 0; jf < 8; jf++)
#pragma unroll
      for (int r = 0; r < 4; r++) {
        const int pp = w * 16 + hi * 4 + r;
        const int nn = jf * 16 + lr;
        sc[pp * NSTATE + nn] = f2bf(accT[jf][r]);
      }
  }
  if (t == 0) dtsum[bh * NCH + ch] = sdl[QC - 1];
}

// ---------------- SSD kernel 2: serial chunk-state combine ----------------
__global__ __launch_bounds__(256)
void k_ssd2(const float* __restrict__ A_log, const float* __restrict__ dtsum,
            unsigned short* __restrict__ ScHt) {
  const int blk = blockIdx.x;
  const int bh = blk >> 3, pg = blk & 7;
  const int t = threadIdx.x;
  const int p = pg * 8 + (t >> 5), n0 = (t & 31) * 4;
  const int h = bh & 63;
  const float Ah = -__expf(A_log[h]);
  float H[4] = {0.f, 0.f, 0.f, 0.f};
  for (int c = 0; c < NCH; c++) {
    size_t base = (((size_t)bh * NCH + c) * PDIM + p) * NSTATE + n0;
    ushort4 sv = *(const ushort4*)&ScHt[base];
    float dec = __expf(Ah * dtsum[bh * NCH + c]);
    ushort4 hv;
    hv.x = f2bf(H[0]); hv.y = f2bf(H[1]); hv.z = f2bf(H[2]); hv.w = f2bf(H[3]);
    *(ushort4*)&ScHt[base] = hv;
    H[0] = dec * H[0] + bf2f(sv.x);
    H[1] = dec * H[1] + bf2f(sv.y);
    H[2] = dec * H[2] + bf2f(sv.z);
    H[3] = dec * H[3] + bf2f(sv.w);
  }
}

// ---------------- SSD kernel 3: inter-chunk Y += decay * C @ H_in ----------------
__global__ __launch_bounds__(256)
void k_ssd3(const unsigned short* __restrict__ bcbf, const unsigned short* __restrict__ Ht,
            const float* __restrict__ dtg, const float* __restrict__ A_log,
            unsigned short* __restrict__ ybuf) {
  __shared__ __align__(16) char smem[33280];
  unsigned short* sCs = (unsigned short*)(smem);
  unsigned short* sHt = (unsigned short*)(smem + 16384);
  float* sdt = (float*)(smem + 32768);
  float* sdl = (float*)(smem + 33024);

  const int bi = blockIdx.x;
  const int ch = bi & 31, h = (bi >> 5) & 63, b = bi >> 11;
  const int bh = b * NH + h;
  const int tok0 = b * LSEQ + ch * QC;
  const int t = threadIdx.x;
  const int w = t >> 6, l = t & 63, lr = l & 15, hi = l >> 4;
  const float Ah = -__expf(A_log[h]);

  {
    const int srow = t >> 4, scol = (t & 15) * 8;
    const unsigned short* gh = Ht + ((size_t)bh * NCH + ch) * (PDIM * NSTATE);
#pragma unroll
    for (int i = 0; i < 4; i++) {
      const unsigned short* gc = bcbf + (size_t)(tok0 + srow + 16 * i) * 256 + 128 + scol;
      GLL(gc, (char*)sCs + i * 4096 + w * 1024);
      GLL(gh + i * 2048 + t * 8, (char*)sHt + i * 4096 + w * 1024);
    }
  }
  if (t < QC) sdt[t] = dtg[(size_t)(tok0 + t) * NH + h];
  __syncthreads();
  if (t < QC) sdl[t] = sdt[t];
  __syncthreads();
  for (int off = 1; off < QC; off <<= 1) {
    float v = 0.f;
    if (t < QC && t >= off) v = sdl[t - off];
    __syncthreads();
    if (t < QC) sdl[t] += v;
    __syncthreads();
  }

  f32x4 acc[4];
#pragma unroll
  for (int jf = 0; jf < 4; jf++) acc[jf] = (f32x4){0.f, 0.f, 0.f, 0.f};
#pragma unroll
  for (int ks = 0; ks < 4; ks++) {
    bf16x8 a = *(const bf16x8*)&sCs[(w * 16 + lr) * 128 + ks * 32 + hi * 8];
#pragma unroll
    for (int jf = 0; jf < 4; jf++) {
      bf16x8 bbq = *(const bf16x8*)&sHt[(jf * 16 + lr) * 128 + ks * 32 + hi * 8];
      acc[jf] = __builtin_amdgcn_mfma_f32_16x16x32_bf16(a, bbq, acc[jf], 0, 0, 0);
    }
  }
#pragma unroll
  for (int jf = 0; jf < 4; jf++)
#pragma unroll
    for (int r = 0; r < 4; r++) {
      const int tt = w * 16 + hi * 4 + r;
      const int pp = jf * 16 + lr;
      const float dec = __expf(Ah * sdl[tt]);
      const size_t o = (size_t)(tok0 + tt) * DI + h * 64 + pp;
      ybuf[o] = f2bf(bf2f(ybuf[o]) + dec * acc[jf][r]);
    }
}

// ---------------- workspace layout (bytes), total ~412.1 MB ----------------
static const size_t OFF_WBF_IN  = 0;
static const size_t OFF_WBF_OUT = 35651584;
static const size_t OFF_WBF_GU  = 52428800;
static const size_t OFF_WBF_DN  = 119537664;
static const size_t OFF_RESID   = 153092096;
static const size_t OFF_HSBF    = 186646528;
static const size_t OFF_PROJ    = 203423744;
static const size_t OFF_XBF     = 274726912;
static const size_t OFF_BCBF    = 308281344;
static const size_t OFF_DTG     = 310378496;
static const size_t OFF_YBUF    = 311427072;
static const size_t OFF_SC      = 344981504;
static const size_t OFF_DTSUM   = 412090368;

extern "C" void kernel_launch(void* const* d_in, const int* in_sizes, int n_in,
                              void* d_out, int out_size, void* d_ws, size_t ws_size,
                              hipStream_t stream) {
  (void)in_sizes; (void)n_in; (void)out_size; (void)ws_size;
  const float* hidden   = (const float*)d_in[1];
  const float* resin    = (const float*)d_in[2];
  const float* w_inproj = (const float*)d_in[3];
  const float* conv_w   = (const float*)d_in[4];
  const float* conv_b   = (const float*)d_in[5];
  const float* A_log    = (const float*)d_in[6];
  const float* Dvec     = (const float*)d_in[7];
  const float* dt_bias  = (const float*)d_in[8];
  const float* w_mix    = (const float*)d_in[9];
  const float* w_outp   = (const float*)d_in[10];
  const float* w_ln1    = (const float*)d_in[11];
  const float* w_ln2    = (const float*)d_in[12];
  const float* w_gu     = (const float*)d_in[13];
  const float* w_dn     = (const float*)d_in[14];

  char* ws = (char*)d_ws;
  unsigned short* wbf_in  = (unsigned short*)(ws + OFF_WBF_IN);
  unsigned short* wbf_out = (unsigned short*)(ws + OFF_WBF_OUT);
  unsigned short* wbf_gu  = (unsigned short*)(ws + OFF_WBF_GU);
  unsigned short* wbf_dn  = (unsigned short*)(ws + OFF_WBF_DN);
  float*          residb  = (float*)(ws + OFF_RESID);
  unsigned short* hsbf    = (unsigned short*)(ws + OFF_HSBF);
  unsigned short* projbf  = (unsigned short*)(ws + OFF_PROJ);
  unsigned short* actbf   = (unsigned short*)(ws + OFF_PROJ);   // alias
  unsigned short* xbf     = (unsigned short*)(ws + OFF_XBF);
  unsigned short* ynormbf = (unsigned short*)(ws + OFF_XBF);    // alias
  unsigned short* bcbf    = (unsigned short*)(ws + OFF_BCBF);
  float*          dtgb    = (float*)(ws + OFF_DTG);
  unsigned short* ybuf    = (unsigned short*)(ws + OFF_YBUF);
  unsigned short* scht    = (unsigned short*)(ws + OFF_SC);
  float*          dtsumb  = (float*)(ws + OFF_DTSUM);

  float* out0 = (float*)d_out;
  float* res2 = out0 + (size_t)T_TOK * HID;

  // 0) all weight conversions in one kernel
  k_cvt_all<<<37376, 256, 0, stream>>>(w_inproj, w_outp, w_gu, w_dn,
                                       wbf_in, wbf_out, wbf_gu, wbf_dn);
  // 1) residual add + input rmsnorm
  k_addnorm<<<T_TOK, 256, 0, stream>>>(hidden, resin, w_ln1, residb, hsbf);
  // 2) in_proj GEMM -> proj bf16 [4096][8704]
  gemm8<0, 256><<<34 * 16, 512, 0, stream>>>(hsbf, wbf_in, HID, DPADR, projbf, nullptr);
  // 3) causal conv + silu -> xbf / bcbf (bf16), fused dt softplus
  k_conv<<<dim3(18, T_TOK), 256, 0, stream>>>(projbf, conv_w, conv_b, dt_bias, xbf, bcbf, dtgb);
  // 4) SSD intra + chunk states
  k_ssd1<<<4096, 256, 0, stream>>>(xbf, bcbf, dtgb, A_log, Dvec, ybuf, scht, dtsumb);
  // 5) SSD serial combine
  k_ssd2<<<1024, 256, 0, stream>>>(A_log, dtsumb, scht);
  // 6) SSD inter-chunk
  k_ssd3<<<4096, 256, 0, stream>>>(bcbf, scht, dtgb, A_log, ybuf);
  // 7) gate + mixer rmsnorm -> ynorm bf16
  k_gatenorm<<<T_TOK, 256, 0, stream>>>(ybuf, projbf, w_mix, ynormbf);
  // 8) out_proj GEMM + residual -> residual2 (output 1)
  gemm8<1, 128><<<8 * 32, 512, 0, stream>>>(ynormbf, wbf_out, DI, HID, res2, residb);
  // 9) pre-FF rmsnorm -> hs2 bf16
  k_rmsnorm_bf<<<T_TOK, 256, 0, stream>>>(res2, w_ln2, hsbf);
  // 10) gate_up GEMM (fused silu-pair epilogue) -> act bf16
  gemm8<2, 256><<<64 * 16, 512, 0, stream>>>(hsbf, wbf_gu, HID, IM, actbf, nullptr);
  // 11) down GEMM -> out (output 0)
  gemm8<3, 128><<<8 * 32, 512, 0, stream>>>(actbf, wbf_dn, IM, HID, out0, nullptr);
}

// Round 12
// 986.551 us; speedup vs baseline: 1.1382x; 1.0083x over previous
//
#include <hip/hip_runtime.h>

// ---------------- problem constants ----------------
#define T_TOK 4096          // BB*L tokens
#define HID   2048
#define DI    4096
#define NH    64
#define PDIM  64
#define NSTATE 128
#define IM    8192
#define LSEQ  2048
#define CONVD 4352          // DI + 2*G*N
#define DPROJ 8512          // 2*DI + 2*G*N + NH
#define DPADR 8704          // padded to 34*256
#define QC    64            // SSD chunk length
#define NCH   32            // chunks per sequence

typedef __bf16 bf16x8 __attribute__((ext_vector_type(8)));
typedef float  f32x4  __attribute__((ext_vector_type(4)));

__device__ __forceinline__ unsigned short f2bf(float f) {
  unsigned u = __float_as_uint(f);
  u = (u + 0x7fffu + ((u >> 16) & 1u)) >> 16;
  return (unsigned short)u;
}
__device__ __forceinline__ float bf2f(unsigned short h) {
  return __uint_as_float(((unsigned)h) << 16);
}
__device__ __forceinline__ float siluf(float x) {
  return x / (1.f + __expf(-x));
}

#define GLL(gaddr, laddr) __builtin_amdgcn_global_load_lds( \
    (const __attribute__((address_space(1))) void*)(gaddr), \
    (__attribute__((address_space(3))) void*)(laddr), 16, 0, 0)

// ---------------- weight conversion helper (gid = 8-elem unit index) ----------------
__device__ __forceinline__ void cvt8(const float* __restrict__ s, unsigned short* __restrict__ d) {
  float4 v0 = *(const float4*)s;
  float4 v1 = *(const float4*)(s + 4);
  unsigned short o[8];
  o[0] = f2bf(v0.x); o[1] = f2bf(v0.y); o[2] = f2bf(v0.z); o[3] = f2bf(v0.w);
  o[4] = f2bf(v1.x); o[5] = f2bf(v1.y); o[6] = f2bf(v1.z); o[7] = f2bf(v1.w);
  *(uint4*)d = *(const uint4*)o;
}

// region thresholds in 8-elem units
#define CV_IN_END  2228224ULL   // DPADR*HID/8
#define CV_OUT_END 3276800ULL   // + 2048*4096/8
#define CV_GU_END  7471104ULL   // + 2*IM*2048/8
#define CV_DN_END  9568256ULL   // + 2048*8192/8

__device__ __forceinline__ void cvt_do(size_t gid,
    const float* __restrict__ w_in, const float* __restrict__ w_out,
    const float* __restrict__ w_gu, const float* __restrict__ w_dn,
    unsigned short* __restrict__ d_in, unsigned short* __restrict__ d_out,
    unsigned short* __restrict__ d_gu, unsigned short* __restrict__ d_dn) {
  if (gid < CV_IN_END) {
    // in_proj: [8512,2048] -> [8704,2048], pad rows zero
    size_t idx8 = gid * 8;
    int r = (int)(idx8 >> 11), k = (int)(idx8 & 2047);
    if (r < DPROJ) {
      cvt8(&w_in[(size_t)r * HID + k], d_in + idx8);
    } else {
      uint4 z = {0, 0, 0, 0};
      *(uint4*)(d_in + idx8) = z;
    }
  } else if (gid < CV_OUT_END) {
    size_t idx8 = (gid - CV_IN_END) * 8;
    cvt8(w_out + idx8, d_out + idx8);
  } else if (gid < CV_GU_END) {
    // gate_up: reorder rows so each 64-row group g = [gate g*32..+31 | up g*32..+31]
    size_t idx8 = (gid - CV_OUT_END) * 8;
    int r = (int)(idx8 >> 11), k = (int)(idx8 & 2047);
    int g = r >> 6, j = r & 63;
    int srcr = (j < 32) ? (g * 32 + j) : (IM + g * 32 + (j - 32));
    cvt8(&w_gu[(size_t)srcr * HID + k], d_gu + idx8);
  } else if (gid < CV_DN_END) {
    size_t idx8 = (gid - CV_GU_END) * 8;
    cvt8(w_dn + idx8, d_dn + idx8);
  }
}

// ---------------- pipelined BMx256 GEMM body (R5/R8/R11 known-good structure) ----------------
// C[M,N] = A[M,K] * W[N,K]^T, M fixed 4096. 512 thr = 8 waves (2M x 4N).
// One barrier + one vmcnt(0) per K-tile (waited loads issued a full tile earlier);
// ds_reads interleaved with MFMA clusters; no intra-tile barriers -> waves drift.
// GEMM scheduling is CLOSED: 3 structured-schedule ports (R6/R7/R10) all lost to
// this loop; setprio removal neutral (R11). ngb = number of GEMM blocks (for the
// bijective XCD swizzle) — must NOT be gridDim.x when fused with cvt blocks.
template <int EPI, int BM>
__device__ __forceinline__ void gemm_body(int bid, int ngb,
    const unsigned short* __restrict__ A, const unsigned short* __restrict__ W,
    int K, int ldo, void* __restrict__ outp, const float* __restrict__ resid) {
  constexpr int MREP  = BM / 32;
  constexpr int ABYT  = BM * 128;
  constexpr int BUFB  = ABYT + 32768;
  constexpr int NTM   = 4096 / BM;
  __shared__ __align__(16) char smem[2 * BUFB];
  const int t = threadIdx.x;
  const int w = t >> 6, l = t & 63;
  const int lr = l & 15, hi = l >> 4;
  const int wr = w >> 2, wc = w & 3;

  // T1: bijective XCD swizzle over tn-major enumeration (ngb % 8 == 0)
  const int q = ngb >> 3;
  const int id2 = (bid & 7) * q + (bid >> 3);
  const int tn = id2 / NTM, tm = id2 % NTM;
  const int m0b = tm * BM, n0b = tn << 8;

  // staging lane constants; source col pre-swizzled (byte bits 5,6 <- row bits 2,3)
  const int srow = t >> 3;
  const int scole = ((t & 7) << 3) ^ ((t & 32) ? 16 : 0) ^ ((t & 64) ? 32 : 0);
  const unsigned short* Ag = A + (size_t)(m0b + srow) * K + scole;
  const unsigned short* Wg = W + (size_t)(n0b + srow) * K + scole;
  const int ldsw = w * 1024;

  // ds_read swizzled byte bases per kk
  const int fa = ((lr & 4) ? 32 : 0) | ((lr & 8) ? 64 : 0);
  const int arow = (wr * (BM / 2) + lr) * 128 + hi * 16;
  const int brow = (wc * 64 + lr) * 128 + hi * 16;
  const int aoff0 = arow ^ fa, aoff1 = (arow + 64) ^ fa;
  const int boff0 = brow ^ fa, boff1 = (brow + 64) ^ fa;

#define ISSUE_A(jt, bb) do {                                                    \
    _Pragma("unroll")                                                           \
    for (int p_ = 0; p_ < BM / 64; ++p_)                                        \
      GLL(Ag + (size_t)(p_ * 64) * K + (size_t)(jt) * 64,                       \
          smem + (bb) * BUFB + p_ * 8192 + ldsw); } while (0)
#define ISSUE_B(jt, bb) do {                                                    \
    _Pragma("unroll")                                                           \
    for (int p_ = 0; p_ < 4; ++p_)                                              \
      GLL(Wg + (size_t)(p_ * 64) * K + (size_t)(jt) * 64,                       \
          smem + (bb) * BUFB + ABYT + p_ * 8192 + ldsw); } while (0)

#define RDF(off, base) (*(const bf16x8*)((base) + (off)))
#define MF(P, x, y, c0, c1, c2, c3) do {                                                     \
    acc[2*(P)  ][0] = __builtin_amdgcn_mfma_f32_16x16x32_bf16((x),(c0),acc[2*(P)  ][0],0,0,0);\
    acc[2*(P)+1][0] = __builtin_amdgcn_mfma_f32_16x16x32_bf16((y),(c0),acc[2*(P)+1][0],0,0,0);\
    acc[2*(P)  ][1] = __builtin_amdgcn_mfma_f32_16x16x32_bf16((x),(c1),acc[2*(P)  ][1],0,0,0);\
    acc[2*(P)+1][1] = __builtin_amdgcn_mfma_f32_16x16x32_bf16((y),(c1),acc[2*(P)+1][1],0,0,0);\
    acc[2*(P)  ][2] = __builtin_amdgcn_mfma_f32_16x16x32_bf16((x),(c2),acc[2*(P)  ][2],0,0,0);\
    acc[2*(P)+1][2] = __builtin_amdgcn_mfma_f32_16x16x32_bf16((y),(c2),acc[2*(P)+1][2],0,0,0);\
    acc[2*(P)  ][3] = __builtin_amdgcn_mfma_f32_16x16x32_bf16((x),(c3),acc[2*(P)  ][3],0,0,0);\
    acc[2*(P)+1][3] = __builtin_amdgcn_mfma_f32_16x16x32_bf16((y),(c3),acc[2*(P)+1][3],0,0,0);\
    } while (0)

  f32x4 acc[MREP][4];
#pragma unroll
  for (int m = 0; m < MREP; m++)
#pragma unroll
    for (int n = 0; n < 4; n++) acc[m][n] = (f32x4){0.f, 0.f, 0.f, 0.f};

  const int nkt = K >> 6;
  // prologue: stage tile 0 into buf 0
  ISSUE_A(0, 0); ISSUE_B(0, 0);

  for (int j = 0; j < nkt; ++j) {
    const int cur = j & 1;
    const char* Ab = smem + cur * BUFB;
    const char* Bb = Ab + ABYT;
    asm volatile("s_waitcnt vmcnt(0)" ::: "memory");   // waits loads issued a full tile ago
    __builtin_amdgcn_s_barrier();                       // all waves' slices resident (WAR-safe)
    __builtin_amdgcn_sched_barrier(0);
    if (j + 1 < nkt) { ISSUE_A(j + 1, cur ^ 1); ISSUE_B(j + 1, cur ^ 1); }
    bf16x8 b0 = RDF(boff0, Bb), b1 = RDF(boff0 + 2048, Bb),
           b2 = RDF(boff0 + 4096, Bb), b3 = RDF(boff0 + 6144, Bb);
    bf16x8 af0 = RDF(aoff0, Ab), af1 = RDF(aoff0 + 2048, Ab);
    bf16x8 af2, af3, b4, b5, b6, b7;
    if constexpr (MREP == 8) {
      af2 = RDF(aoff0 + 4096, Ab); af3 = RDF(aoff0 + 6144, Ab);
      MF(0, af0, af1, b0, b1, b2, b3);
      af0 = RDF(aoff0 + 8192, Ab); af1 = RDF(aoff0 + 10240, Ab);
      MF(1, af2, af3, b0, b1, b2, b3);
      af2 = RDF(aoff0 + 12288, Ab); af3 = RDF(aoff0 + 14336, Ab);
      MF(2, af0, af1, b0, b1, b2, b3);
      b4 = RDF(boff1, Bb); b5 = RDF(boff1 + 2048, Bb);
      b6 = RDF(boff1 + 4096, Bb); b7 = RDF(boff1 + 6144, Bb);
      af0 = RDF(aoff1, Ab); af1 = RDF(aoff1 + 2048, Ab);
      MF(3, af2, af3, b0, b1, b2, b3);
      af2 = RDF(aoff1 + 4096, Ab); af3 = RDF(aoff1 + 6144, Ab);
      MF(0, af0, af1, b4, b5, b6, b7);
      af0 = RDF(aoff1 + 8192, Ab); af1 = RDF(aoff1 + 10240, Ab);
      MF(1, af2, af3, b4, b5, b6, b7);
      af2 = RDF(aoff1 + 12288, Ab); af3 = RDF(aoff1 + 14336, Ab);
      MF(2, af0, af1, b4, b5, b6, b7);
      MF(3, af2, af3, b4, b5, b6, b7);
    } else {
      af2 = RDF(aoff0 + 4096, Ab); af3 = RDF(aoff0 + 6144, Ab);
      MF(0, af0, af1, b0, b1, b2, b3);
      b4 = RDF(boff1, Bb); b5 = RDF(boff1 + 2048, Bb);
      b6 = RDF(boff1 + 4096, Bb); b7 = RDF(boff1 + 6144, Bb);
      af0 = RDF(aoff1, Ab); af1 = RDF(aoff1 + 2048, Ab);
      MF(1, af2, af3, b0, b1, b2, b3);
      af2 = RDF(aoff1 + 4096, Ab); af3 = RDF(aoff1 + 6144, Ab);
      MF(0, af0, af1, b4, b5, b6, b7);
      MF(1, af2, af3, b4, b5, b6, b7);
    }
  }

  if constexpr (EPI == 0) {
    unsigned short* op = (unsigned short*)outp;
#pragma unroll
    for (int m = 0; m < MREP; m++)
#pragma unroll
      for (int n = 0; n < 4; n++)
#pragma unroll
        for (int r = 0; r < 4; r++) {
          int row = m0b + wr * (BM / 2) + m * 16 + hi * 4 + r;
          int col = n0b + wc * 64 + n * 16 + lr;
          op[(size_t)row * ldo + col] = f2bf(acc[m][n][r]);
        }
  } else if constexpr (EPI == 2) {
    unsigned short* op = (unsigned short*)outp;
    const int gbase = (n0b + wc * 64) >> 1;
#pragma unroll
    for (int m = 0; m < MREP; m++)
#pragma unroll
      for (int n = 0; n < 2; n++)
#pragma unroll
        for (int r = 0; r < 4; r++) {
          int row = m0b + wr * (BM / 2) + m * 16 + hi * 4 + r;
          int col = gbase + n * 16 + lr;
          float g = acc[m][n][r], u = acc[m][n + 2][r];
          op[(size_t)row * ldo + col] = f2bf(siluf(g) * u);
        }
  } else {
    float* op = (float*)outp;
#pragma unroll
    for (int m = 0; m < MREP; m++)
#pragma unroll
      for (int n = 0; n < 4; n++)
#pragma unroll
        for (int r = 0; r < 4; r++) {
          int row = m0b + wr * (BM / 2) + m * 16 + hi * 4 + r;
          int col = n0b + wc * 64 + n * 16 + lr;
          float v = acc[m][n][r];
          if constexpr (EPI == 1) v += resid[(size_t)row * ldo + col];
          op[(size_t)row * ldo + col] = v;
        }
  }
#undef ISSUE_A
#undef ISSUE_B
#undef RDF
#undef MF
}

template <int EPI, int BM>
__global__ __launch_bounds__(512, 2)
void gemm8(const unsigned short* __restrict__ A, const unsigned short* __restrict__ W,
           int K, int ldo, void* __restrict__ outp, const float* __restrict__ resid) {
  gemm_body<EPI, BM>((int)blockIdx.x, (int)gridDim.x, A, W, K, ldo, outp, resid);
}

// in_proj GEMM fused with out/gu/dn weight conversion: blocks [0,ngb) do GEMM
// tiles, blocks [ngb, ...) stream the f32->bf16 conversions (backfill CUs as
// GEMM tiles retire; cvt uses the ~5 TB/s of HBM headroom the GEMM leaves).
__global__ __launch_bounds__(512, 2)
void k_inproj_fused(const unsigned short* __restrict__ A, const unsigned short* __restrict__ Wbf,
                    int ngb, unsigned short* __restrict__ projbf,
                    const float* __restrict__ w_out, const float* __restrict__ w_gu,
                    const float* __restrict__ w_dn, unsigned short* __restrict__ d_out,
                    unsigned short* __restrict__ d_gu, unsigned short* __restrict__ d_dn) {
  if ((int)blockIdx.x < ngb) {
    gemm_body<0, 256>((int)blockIdx.x, ngb, A, Wbf, HID, DPADR, projbf, nullptr);
  } else {
    size_t gid = CV_IN_END + (size_t)((int)blockIdx.x - ngb) * 512 + threadIdx.x;
    cvt_do(gid, nullptr, w_out, w_gu, w_dn, nullptr, d_out, d_gu, d_dn);
  }
}

// ---------------- norms ----------------
__device__ __forceinline__ float block_reduce_sum256(float v, float* sred) {
#pragma unroll
  for (int m = 32; m; m >>= 1) v += __shfl_xor(v, m);
  int t = threadIdx.x;
  if ((t & 63) == 0) sred[t >> 6] = v;
  __syncthreads();
  return sred[0] + sred[1] + sred[2] + sred[3];
}

// addnorm fused with in_proj weight conversion (blocks >= T_TOK do cvt)
__global__ __launch_bounds__(256)
void k_addnorm(const float* __restrict__ hin, const float* __restrict__ rin,
               const float* __restrict__ wln, float* __restrict__ rout,
               unsigned short* __restrict__ hbf,
               const float* __restrict__ w_in, unsigned short* __restrict__ d_in) {
  if ((int)blockIdx.x >= T_TOK) {
    size_t gid = (size_t)((int)blockIdx.x - T_TOK) * 256 + threadIdx.x;
    cvt_do(gid, w_in, nullptr, nullptr, nullptr, d_in, nullptr, nullptr, nullptr);
    return;
  }
  __shared__ float sred[4];
  const int tok = blockIdx.x, t = threadIdx.x;
  const size_t base = (size_t)tok * HID + t * 8;
  float4 a0 = *(const float4*)&hin[base];
  float4 a1 = *(const float4*)&hin[base + 4];
  float4 b0 = *(const float4*)&rin[base];
  float4 b1 = *(const float4*)&rin[base + 4];
  float v[8] = {a0.x + b0.x, a0.y + b0.y, a0.z + b0.z, a0.w + b0.w,
                a1.x + b1.x, a1.y + b1.y, a1.z + b1.z, a1.w + b1.w};
  float ss = 0.f;
#pragma unroll
  for (int j = 0; j < 8; j++) ss += v[j] * v[j];
  float tot = block_reduce_sum256(ss, sred);
  float rms = rsqrtf(tot * (1.f / HID) + 1e-5f);
  *(float4*)&rout[base] = (float4){v[0], v[1], v[2], v[3]};
  *(float4*)&rout[base + 4] = (float4){v[4], v[5], v[6], v[7]};
  float4 w0 = *(const float4*)&wln[t * 8];
  float4 w1 = *(const float4*)&wln[t * 8 + 4];
  float wa[8] = {w0.x, w0.y, w0.z, w0.w, w1.x, w1.y, w1.z, w1.w};
  unsigned short o[8];
#pragma unroll
  for (int j = 0; j < 8; j++) o[j] = f2bf(v[j] * rms * wa[j]);
  *(ushort4*)&hbf[base] = *(ushort4*)&o[0];
  *(ushort4*)&hbf[base + 4] = *(ushort4*)&o[4];
}

__global__ __launch_bounds__(256)
void k_rmsnorm_bf(const float* __restrict__ src, const float* __restrict__ wln,
                  unsigned short* __restrict__ dst) {
  __shared__ float sred[4];
  const int tok = blockIdx.x, t = threadIdx.x;
  const size_t base = (size_t)tok * HID + t * 8;
  float4 a0 = *(const float4*)&src[base];
  float4 a1 = *(const float4*)&src[base + 4];
  float v[8] = {a0.x, a0.y, a0.z, a0.w, a1.x, a1.y, a1.z, a1.w};
  float ss = 0.f;
#pragma unroll
  for (int j = 0; j < 8; j++) ss += v[j] * v[j];
  float tot = block_reduce_sum256(ss, sred);
  float rms = rsqrtf(tot * (1.f / HID) + 1e-5f);
  float4 w0 = *(const float4*)&wln[t * 8];
  float4 w1 = *(const float4*)&wln[t * 8 + 4];
  float wa[8] = {w0.x, w0.y, w0.z, w0.w, w1.x, w1.y, w1.z, w1.w};
  unsigned short o[8];
#pragma unroll
  for (int j = 0; j < 8; j++) o[j] = f2bf(v[j] * rms * wa[j]);
  *(ushort4*)&dst[base] = *(ushort4*)&o[0];
  *(ushort4*)&dst[base + 4] = *(ushort4*)&o[4];
}

__global__ __launch_bounds__(256)
void k_gatenorm(const unsigned short* __restrict__ ybuf, const unsigned short* __restrict__ projbf,
                const float* __restrict__ wmix, unsigned short* __restrict__ ynorm) {
  __shared__ float sred[4];
  const int tok = blockIdx.x, t = threadIdx.x;
  const size_t yb = (size_t)tok * DI;
  const size_t pb = (size_t)tok * DPADR;
  float g[16];
  float ss = 0.f;
#pragma unroll
  for (int j = 0; j < 16; j++) {
    int idx = j * 256 + t;
    float yv = bf2f(ybuf[yb + idx]);
    float z = bf2f(projbf[pb + idx]);
    float gg = yv * siluf(z);
    g[j] = gg;
    ss += gg * gg;
  }
  float tot = block_reduce_sum256(ss, sred);
  float rms = rsqrtf(tot * (1.f / DI) + 1e-5f);
#pragma unroll
  for (int j = 0; j < 16; j++) {
    int idx = j * 256 + t;
    ynorm[yb + idx] = f2bf(g[j] * rms * wmix[idx]);
  }
}

// ---------------- conv (depthwise causal K=4) + silu + fused dt softplus ----------------
__global__ __launch_bounds__(256)
void k_conv(const unsigned short* __restrict__ projbf, const float* __restrict__ cw,
            const float* __restrict__ cb, const float* __restrict__ dt_bias,
            unsigned short* __restrict__ xbf, unsigned short* __restrict__ bcbf,
            float* __restrict__ dtg) {
  const int c = blockIdx.x * 256 + threadIdx.x;   // 0..4607
  const int tk = blockIdx.y;                      // token
  if (c < CONVD) {
    const int lpos = tk & (LSEQ - 1);
    float4 wv = *(const float4*)&cw[c * 4];
    float wk[4] = {wv.x, wv.y, wv.z, wv.w};
    float acc = cb[c];
#pragma unroll
    for (int k = 0; k < 4; k++) {
      int lp = lpos - 3 + k;
      if (lp >= 0) acc += bf2f(projbf[(size_t)(tk - 3 + k) * DPADR + DI + c]) * wk[k];
    }
    unsigned short r = f2bf(siluf(acc));
    if (c < DI) xbf[(size_t)tk * DI + c] = r;
    else        bcbf[(size_t)tk * 256 + (c - DI)] = r;
  } else if (c < CONVD + NH) {
    const int hh = c - CONVD;
    float x = bf2f(projbf[(size_t)tk * DPADR + DI + c]) + dt_bias[hh];
    float dt = (x > 20.f) ? x : log1pf(__expf(x));
    dtg[(size_t)tk * NH + hh] = dt;
  }
}

// ---------------- SSD kernel 1: per (b,h,chunk) intra + chunk-state ----------------
__global__ __launch_bounds__(256)
void k_ssd1(const unsigned short* __restrict__ xbf, const unsigned short* __restrict__ bcbf,
            const float* __restrict__ dtg, const float* __restrict__ A_log,
            const float* __restrict__ Dv, unsigned short* __restrict__ ybuf,
            unsigned short* __restrict__ Sc, float* __restrict__ dtsum) {
  __shared__ __align__(16) char smem[60928];
  unsigned short* sBs  = (unsigned short*)(smem);          // [64][128]
  unsigned short* sCs  = (unsigned short*)(smem + 16384);  // [64][128]
  unsigned short* sMs  = (unsigned short*)(smem + 16384);  // alias: [64][72]
  unsigned short* sBsT = (unsigned short*)(smem + 32768);  // [128][72] scaled B^T
  unsigned short* sXsT = (unsigned short*)(smem + 51200);  // [64][72]  x^T
  float* sdt = (float*)(smem + 60416);
  float* sdl = (float*)(smem + 60672);

  const int bi = blockIdx.x;
  const int ch = bi & 31, h = (bi >> 5) & 63, b = bi >> 11;
  const int bh = b * NH + h;
  const int tok0 = b * LSEQ + ch * QC;
  const int t = threadIdx.x;
  const int w = t >> 6, l = t & 63, lr = l & 15, hi = l >> 4;
  const float Ah = -__expf(A_log[h]);
  const float Dh = Dv[h];

  {
    const int srow = t >> 4, scol = (t & 15) * 8;
#pragma unroll
    for (int i = 0; i < 4; i++) {
      const unsigned short* gb = bcbf + (size_t)(tok0 + srow + 16 * i) * 256 + scol;
      GLL(gb, (char*)sBs + i * 4096 + w * 1024);
      GLL(gb + 128, (char*)sCs + i * 4096 + w * 1024);
    }
  }
  if (t < QC) sdt[t] = dtg[(size_t)(tok0 + t) * NH + h];
  __syncthreads();
  if (t < QC) sdl[t] = sdt[t];
  __syncthreads();
  for (int off = 1; off < QC; off <<= 1) {
    float v = 0.f;
    if (t < QC && t >= off) v = sdl[t - off];
    __syncthreads();
    if (t < QC) sdl[t] += v;
    __syncthreads();
  }

  {
    const int s = t >> 2;
    const float DlQ = sdl[QC - 1];
    const float csc = __expf(Ah * (DlQ - sdl[s])) * sdt[s];
    const int n0 = (t & 3) * 32;
#pragma unroll
    for (int j = 0; j < 32; j++) {
      float bv = bf2f(sBs[s * 128 + n0 + j]);
      sBsT[(n0 + j) * 72 + s] = f2bf(csc * bv);
    }
    const int p0 = (t & 3) * 16;
    const unsigned short* gx = xbf + (size_t)(tok0 + s) * DI + h * 64 + p0;
    union { uint4 v; unsigned short u[8]; } x0, x1;
    x0.v = *(const uint4*)gx;
    x1.v = *(const uint4*)(gx + 8);
#pragma unroll
    for (int j = 0; j < 8; j++) {
      sXsT[(p0 + j) * 72 + s] = x0.u[j];
      sXsT[(p0 + 8 + j) * 72 + s] = x1.u[j];
    }
  }
  __syncthreads();

  f32x4 accS[4];
#pragma unroll
  for (int jf = 0; jf < 4; jf++) accS[jf] = (f32x4){0.f, 0.f, 0.f, 0.f};
#pragma unroll
  for (int ks = 0; ks < 4; ks++) {
    bf16x8 a = *(const bf16x8*)&sBs[(w * 16 + lr) * 128 + ks * 32 + hi * 8];
#pragma unroll
    for (int jf = 0; jf < 4; jf++) {
      bf16x8 bbq = *(const bf16x8*)&sCs[(jf * 16 + lr) * 128 + ks * 32 + hi * 8];
      accS[jf] = __builtin_amdgcn_mfma_f32_16x16x32_bf16(a, bbq, accS[jf], 0, 0, 0);
    }
  }
  __syncthreads();

  {
    const int s0 = w * 16 + hi * 4;
#pragma unroll
    for (int jf = 0; jf < 4; jf++) {
      const int tt = jf * 16 + lr;
      const float dlt = sdl[tt];
      unsigned short mv[4];
#pragma unroll
      for (int r = 0; r < 4; r++) {
        const int ss = s0 + r;
        float val = 0.f;
        if (ss <= tt) val = accS[jf][r] * __expf(Ah * (dlt - sdl[ss])) * sdt[ss];
        mv[r] = f2bf(val);
      }
      *(ushort4*)&sMs[tt * 72 + s0] = *(ushort4*)mv;
    }
  }
  __syncthreads();

  {
    f32x4 accY[4];
#pragma unroll
    for (int jf = 0; jf < 4; jf++) accY[jf] = (f32x4){0.f, 0.f, 0.f, 0.f};
#pragma unroll
    for (int ks = 0; ks < 2; ks++) {
      bf16x8 a = *(const bf16x8*)&sMs[(w * 16 + lr) * 72 + ks * 32 + hi * 8];
#pragma unroll
      for (int jf = 0; jf < 4; jf++) {
        bf16x8 bbq = *(const bf16x8*)&sXsT[(jf * 16 + lr) * 72 + ks * 32 + hi * 8];
        accY[jf] = __builtin_amdgcn_mfma_f32_16x16x32_bf16(a, bbq, accY[jf], 0, 0, 0);
      }
    }
#pragma unroll
    for (int jf = 0; jf < 4; jf++)
#pragma unroll
      for (int r = 0; r < 4; r++) {
        const int tt = w * 16 + hi * 4 + r;
        const int pp = jf * 16 + lr;
        float xv = bf2f(sXsT[pp * 72 + tt]);
        ybuf[(size_t)(tok0 + tt) * DI + h * 64 + pp] = f2bf(accY[jf][r] + Dh * xv);
      }
  }

  {
    f32x4 accT[8];
#pragma unroll
    for (int jf = 0; jf < 8; jf++) accT[jf] = (f32x4){0.f, 0.f, 0.f, 0.f};
#pragma unroll
    for (int ks = 0; ks < 2; ks++) {
      bf16x8 a = *(const bf16x8*)&sXsT[(w * 16 + lr) * 72 + ks * 32 + hi * 8];
#pragma unroll
      for (int jf = 0; jf < 8; jf++) {
        bf16x8 bbq = *(const bf16x8*)&sBsT[(jf * 16 + lr) * 72 + ks * 32 + hi * 8];
        accT[jf] = __builtin_amdgcn_mfma_f32_16x16x32_bf16(a, bbq, accT[jf], 0, 0, 0);
      }
    }
    unsigned short* sc = Sc + ((size_t)bh * NCH + ch) * (PDIM * NSTATE);
#pragma unroll
    for (int jf = 0; jf < 8; jf++)
#pragma unroll
      for (int r = 0; r < 4; r++) {
        const int pp = w * 16 + hi * 4 + r;
        const int nn = jf * 16 + lr;
        sc[pp * NSTATE + nn] = f2bf(accT[jf][r]);
      }
  }
  if (t == 0) dtsum[bh * NCH + ch] = sdl[QC - 1];
}

// ---------------- SSD kernel 2: serial chunk-state combine ----------------
__global__ __launch_bounds__(256)
void k_ssd2(const float* __restrict__ A_log, const float* __restrict__ dtsum,
            unsigned short* __restrict__ ScHt) {
  const int blk = blockIdx.x;
  const int bh = blk >> 3, pg = blk & 7;
  const int t = threadIdx.x;
  const int p = pg * 8 + (t >> 5), n0 = (t & 31) * 4;
  const int h = bh & 63;
  const float Ah = -__expf(A_log[h]);
  float H[4] = {0.f, 0.f, 0.f, 0.f};
  for (int c = 0; c < NCH; c++) {
    size_t base = (((size_t)bh * NCH + c) * PDIM + p) * NSTATE + n0;
    ushort4 sv = *(const ushort4*)&ScHt[base];
    float dec = __expf(Ah * dtsum[bh * NCH + c]);
    ushort4 hv;
    hv.x = f2bf(H[0]); hv.y = f2bf(H[1]); hv.z = f2bf(H[2]); hv.w = f2bf(H[3]);
    *(ushort4*)&ScHt[base] = hv;
    H[0] = dec * H[0] + bf2f(sv.x);
    H[1] = dec * H[1] + bf2f(sv.y);
    H[2] = dec * H[2] + bf2f(sv.z);
    H[3] = dec * H[3] + bf2f(sv.w);
  }
}

// ---------------- SSD kernel 3: inter-chunk Y += decay * C @ H_in ----------------
__global__ __launch_bounds__(256)
void k_ssd3(const unsigned short* __restrict__ bcbf, const unsigned short* __restrict__ Ht,
            const float* __restrict__ dtg, const float* __restrict__ A_log,
            unsigned short* __restrict__ ybuf) {
  __shared__ __align__(16) char smem[33280];
  unsigned short* sCs = (unsigned short*)(smem);
  unsigned short* sHt = (unsigned short*)(smem + 16384);
  float* sdt = (float*)(smem + 32768);
  float* sdl = (float*)(smem + 33024);

  const int bi = blockIdx.x;
  const int ch = bi & 31, h = (bi >> 5) & 63, b = bi >> 11;
  const int bh = b * NH + h;
  const int tok0 = b * LSEQ + ch * QC;
  const int t = threadIdx.x;
  const int w = t >> 6, l = t & 63, lr = l & 15, hi = l >> 4;
  const float Ah = -__expf(A_log[h]);

  {
    const int srow = t >> 4, scol = (t & 15) * 8;
    const unsigned short* gh = Ht + ((size_t)bh * NCH + ch) * (PDIM * NSTATE);
#pragma unroll
    for (int i = 0; i < 4; i++) {
      const unsigned short* gc = bcbf + (size_t)(tok0 + srow + 16 * i) * 256 + 128 + scol;
      GLL(gc, (char*)sCs + i * 4096 + w * 1024);
      GLL(gh + i * 2048 + t * 8, (char*)sHt + i * 4096 + w * 1024);
    }
  }
  if (t < QC) sdt[t] = dtg[(size_t)(tok0 + t) * NH + h];
  __syncthreads();
  if (t < QC) sdl[t] = sdt[t];
  __syncthreads();
  for (int off = 1; off < QC; off <<= 1) {
    float v = 0.f;
    if (t < QC && t >= off) v = sdl[t - off];
    __syncthreads();
    if (t < QC) sdl[t] += v;
    __syncthreads();
  }

  f32x4 acc[4];
#pragma unroll
  for (int jf = 0; jf < 4; jf++) acc[jf] = (f32x4){0.f, 0.f, 0.f, 0.f};
#pragma unroll
  for (int ks = 0; ks < 4; ks++) {
    bf16x8 a = *(const bf16x8*)&sCs[(w * 16 + lr) * 128 + ks * 32 + hi * 8];
#pragma unroll
    for (int jf = 0; jf < 4; jf++) {
      bf16x8 bbq = *(const bf16x8*)&sHt[(jf * 16 + lr) * 128 + ks * 32 + hi * 8];
      acc[jf] = __builtin_amdgcn_mfma_f32_16x16x32_bf16(a, bbq, acc[jf], 0, 0, 0);
    }
  }
#pragma unroll
  for (int jf = 0; jf < 4; jf++)
#pragma unroll
    for (int r = 0; r < 4; r++) {
      const int tt = w * 16 + hi * 4 + r;
      const int pp = jf * 16 + lr;
      const float dec = __expf(Ah * sdl[tt]);
      const size_t o = (size_t)(tok0 + tt) * DI + h * 64 + pp;
      ybuf[o] = f2bf(bf2f(ybuf[o]) + dec * acc[jf][r]);
    }
}

// ---------------- workspace layout (bytes), total ~412.1 MB ----------------
static const size_t OFF_WBF_IN  = 0;
static const size_t OFF_WBF_OUT = 35651584;
static const size_t OFF_WBF_GU  = 52428800;
static const size_t OFF_WBF_DN  = 119537664;
static const size_t OFF_RESID   = 153092096;
static const size_t OFF_HSBF    = 186646528;
static const size_t OFF_PROJ    = 203423744;
static const size_t OFF_XBF     = 274726912;
static const size_t OFF_BCBF    = 308281344;
static const size_t OFF_DTG     = 310378496;
static const size_t OFF_YBUF    = 311427072;
static const size_t OFF_SC      = 344981504;
static const size_t OFF_DTSUM   = 412090368;

extern "C" void kernel_launch(void* const* d_in, const int* in_sizes, int n_in,
                              void* d_out, int out_size, void* d_ws, size_t ws_size,
                              hipStream_t stream) {
  (void)in_sizes; (void)n_in; (void)out_size; (void)ws_size;
  const float* hidden   = (const float*)d_in[1];
  const float* resin    = (const float*)d_in[2];
  const float* w_inproj = (const float*)d_in[3];
  const float* conv_w   = (const float*)d_in[4];
  const float* conv_b   = (const float*)d_in[5];
  const float* A_log    = (const float*)d_in[6];
  const float* Dvec     = (const float*)d_in[7];
  const float* dt_bias  = (const float*)d_in[8];
  const float* w_mix    = (const float*)d_in[9];
  const float* w_outp   = (const float*)d_in[10];
  const float* w_ln1    = (const float*)d_in[11];
  const float* w_ln2    = (const float*)d_in[12];
  const float* w_gu     = (const float*)d_in[13];
  const float* w_dn     = (const float*)d_in[14];

  char* ws = (char*)d_ws;
  unsigned short* wbf_in  = (unsigned short*)(ws + OFF_WBF_IN);
  unsigned short* wbf_out = (unsigned short*)(ws + OFF_WBF_OUT);
  unsigned short* wbf_gu  = (unsigned short*)(ws + OFF_WBF_GU);
  unsigned short* wbf_dn  = (unsigned short*)(ws + OFF_WBF_DN);
  float*          residb  = (float*)(ws + OFF_RESID);
  unsigned short* hsbf    = (unsigned short*)(ws + OFF_HSBF);
  unsigned short* projbf  = (unsigned short*)(ws + OFF_PROJ);
  unsigned short* actbf   = (unsigned short*)(ws + OFF_PROJ);   // alias
  unsigned short* xbf     = (unsigned short*)(ws + OFF_XBF);
  unsigned short* ynormbf = (unsigned short*)(ws + OFF_XBF);    // alias
  unsigned short* bcbf    = (unsigned short*)(ws + OFF_BCBF);
  float*          dtgb    = (float*)(ws + OFF_DTG);
  unsigned short* ybuf    = (unsigned short*)(ws + OFF_YBUF);
  unsigned short* scht    = (unsigned short*)(ws + OFF_SC);
  float*          dtsumb  = (float*)(ws + OFF_DTSUM);

  float* out0 = (float*)d_out;
  float* res2 = out0 + (size_t)T_TOK * HID;

  // 1) residual add + input rmsnorm, fused with in_proj weight cvt
  //    grid = 4096 addnorm blocks + 8704 cvt blocks (CV_IN_END/256)
  k_addnorm<<<T_TOK + 8704, 256, 0, stream>>>(hidden, resin, w_ln1, residb, hsbf,
                                              w_inproj, wbf_in);
  // 2) in_proj GEMM (544 blocks) fused with out/gu/dn weight cvt (14336 blocks)
  k_inproj_fused<<<544 + 14336, 512, 0, stream>>>(hsbf, wbf_in, 544, projbf,
                                                  w_outp, w_gu, w_dn,
                                                  wbf_out, wbf_gu, wbf_dn);
  // 3) causal conv + silu -> xbf / bcbf (bf16), fused dt softplus
  k_conv<<<dim3(18, T_TOK), 256, 0, stream>>>(projbf, conv_w, conv_b, dt_bias, xbf, bcbf, dtgb);
  // 4) SSD intra + chunk states
  k_ssd1<<<4096, 256, 0, stream>>>(xbf, bcbf, dtgb, A_log, Dvec, ybuf, scht, dtsumb);
  // 5) SSD serial combine
  k_ssd2<<<1024, 256, 0, stream>>>(A_log, dtsumb, scht);
  // 6) SSD inter-chunk
  k_ssd3<<<4096, 256, 0, stream>>>(bcbf, scht, dtgb, A_log, ybuf);
  // 7) gate + mixer rmsnorm -> ynorm bf16
  k_gatenorm<<<T_TOK, 256, 0, stream>>>(ybuf, projbf, w_mix, ynormbf);
  // 8) out_proj GEMM + residual -> residual2 (output 1)
  gemm8<1, 128><<<8 * 32, 512, 0, stream>>>(ynormbf, wbf_out, DI, HID, res2, residb);
  // 9) pre-FF rmsnorm -> hs2 bf16
  k_rmsnorm_bf<<<T_TOK, 256, 0, stream>>>(res2, w_ln2, hsbf);
  // 10) gate_up GEMM (fused silu-pair epilogue) -> act bf16
  gemm8<2, 256><<<64 * 16, 512, 0, stream>>>(hsbf, wbf_gu, HID, IM, actbf, nullptr);
  // 11) down GEMM -> out (output 0)
  gemm8<3, 128><<<8 * 32, 512, 0, stream>>>(actbf, wbf_dn, IM, HID, out0, nullptr);
}